// Round 17
// baseline (218.658 us; speedup 1.0000x reference)
//
#include <hip/hip_runtime.h>
#include <math.h>

// Shapes (fixed)
#define S_  2048
#define B_  2
#define D_  512
#define H_  8
#define DH_ 64
#define E_  8
#define F_  1024
#define N_  4096   // S_*B_
#define NPAIR_ 8192

typedef __attribute__((ext_vector_type(4))) float f32x4;
typedef __attribute__((ext_vector_type(8))) short short8;
typedef unsigned short u16;

__device__ __forceinline__ u16 f2bf(float f) {
  unsigned u = __builtin_bit_cast(unsigned, f);
  u += 0x7fffu + ((u >> 16) & 1u);
  return (u16)(u >> 16);
}
__device__ __forceinline__ float bf2f(u16 h) {
  unsigned u = ((unsigned)h) << 16;
  return __builtin_bit_cast(float, u);
}

// ---------------------------------------------------------------------------
// src -> split bf16 (hi, lo). 2M elements, 8/thread.
// ---------------------------------------------------------------------------
__global__ __launch_bounds__(256) void src_split(const float* __restrict__ in,
                                                 u16* __restrict__ hi,
                                                 u16* __restrict__ lo) {
  size_t i = ((size_t)blockIdx.x * 256 + threadIdx.x) * 8;
  float f[8];
  *(float4*)&f[0] = *(const float4*)&in[i];
  *(float4*)&f[4] = *(const float4*)&in[i + 4];
  short8 h, l;
#pragma unroll
  for (int j = 0; j < 8; ++j) {
    u16 a = f2bf(f[j]);
    h[j] = (short)a;
    l[j] = (short)f2bf(f[j] - bf2f(a));
  }
  *(short8*)&hi[i] = h;
  *(short8*)&lo[i] = l;
}

// ---------------------------------------------------------------------------
// Weight transpose + split (device body): Whi/Wlo[n][k] = split(W[k][n]).
// ---------------------------------------------------------------------------
__device__ __forceinline__ void wsplit_body(const float* __restrict__ W,
                                            u16* __restrict__ Whi,
                                            u16* __restrict__ Wlo,
                                            int Nn, int K, int kb, int nb) {
  __shared__ u16 Th[64][72];
  __shared__ u16 Tl[64][72];
  int r = threadIdx.x >> 2, c0 = (threadIdx.x & 3) * 16;
  const float* wp = &W[(size_t)(kb + r) * Nn + nb + c0];
#pragma unroll
  for (int c = 0; c < 16; c += 4) {
    float4 t = *(const float4*)&wp[c];
    float f[4] = {t.x, t.y, t.z, t.w};
#pragma unroll
    for (int j = 0; j < 4; ++j) {
      u16 a = f2bf(f[j]);
      Th[r][c0 + c + j] = a;
      Tl[r][c0 + c + j] = f2bf(f[j] - bf2f(a));
    }
  }
  __syncthreads();
  short8 h0, h1, l0, l1;
#pragma unroll
  for (int j = 0; j < 8; ++j) {
    h0[j] = (short)Th[c0 + j][r];     h1[j] = (short)Th[c0 + 8 + j][r];
    l0[j] = (short)Tl[c0 + j][r];     l1[j] = (short)Tl[c0 + 8 + j][r];
  }
  size_t ob = (size_t)(nb + r) * K + kb + c0;
  *(short8*)&Whi[ob] = h0;  *(short8*)&Whi[ob + 8] = h1;
  *(short8*)&Wlo[ob] = l0;  *(short8*)&Wlo[ob + 8] = l1;
}

// One launch for Wq/Wk/Wv/Wo splits. grid (8,8,4).
__global__ __launch_bounds__(256) void wsplit_all(const float* __restrict__ Wq,
                                                  const float* __restrict__ Wk,
                                                  const float* __restrict__ Wv,
                                                  const float* __restrict__ Wo,
                                                  u16* __restrict__ Wqkv_hi,
                                                  u16* __restrict__ Wqkv_lo,
                                                  u16* __restrict__ Wo_hi,
                                                  u16* __restrict__ Wo_lo) {
  int z = blockIdx.z;
  const float* W = (z == 0) ? Wq : (z == 1) ? Wk : (z == 2) ? Wv : Wo;
  u16* Whi = (z == 3) ? Wo_hi : Wqkv_hi + (size_t)z * 512 * 512;
  u16* Wlo = (z == 3) ? Wo_lo : Wqkv_lo + (size_t)z * 512 * 512;
  wsplit_body(W, Whi, Wlo, 512, 512, blockIdx.y * 64, blockIdx.x * 64);
}

// ---------------------------------------------------------------------------
// Plain bf16 weight transpose for MoE, W1+W2 in ONE launch.
// ---------------------------------------------------------------------------
__global__ __launch_bounds__(256) void wtrans_all(const float* __restrict__ W1,
                                                  const float* __restrict__ W2,
                                                  u16* __restrict__ W1t,
                                                  u16* __restrict__ W2t) {
  int z = blockIdx.z;
  const float* W;
  u16* Wt;
  int K, Nn, e;
  if (z < 8) {
    if (blockIdx.y >= 8) return;
    W = W1; Wt = W1t; K = 512; Nn = 1024; e = z;
  } else {
    if (blockIdx.x >= 8) return;
    W = W2; Wt = W2t; K = 1024; Nn = 512; e = z - 8;
  }
  size_t eo = (size_t)e * K * Nn;
  __shared__ u16 T[64][72];
  int kb = blockIdx.y * 64, nb = blockIdx.x * 64;
  int r = threadIdx.x >> 2, c0 = (threadIdx.x & 3) * 16;
  const float* wp = &W[eo + (size_t)(kb + r) * Nn + nb + c0];
#pragma unroll
  for (int c = 0; c < 16; c += 4) {
    float4 t = *(const float4*)&wp[c];
    T[r][c0 + c + 0] = f2bf(t.x);
    T[r][c0 + c + 1] = f2bf(t.y);
    T[r][c0 + c + 2] = f2bf(t.z);
    T[r][c0 + c + 3] = f2bf(t.w);
  }
  __syncthreads();
  short8 s0, s1;
#pragma unroll
  for (int j = 0; j < 8; ++j) {
    s0[j] = (short)T[c0 + j][r];
    s1[j] = (short)T[c0 + 8 + j][r];
  }
  *(short8*)&Wt[eo + (size_t)(nb + r) * K + kb + c0] = s0;
  *(short8*)&Wt[eo + (size_t)(nb + r) * K + kb + c0 + 8] = s1;
}

// ---------------------------------------------------------------------------
// Fused QKV split-bf16 MFMA GEMM + RoPE. M=4096, N=1536, K=512.
// Flat XCD-pinned grid (384 = 8 xcd x 4 m x 12 n).
// ---------------------------------------------------------------------------
__global__ __launch_bounds__(256) void qkv_mfma(const u16* __restrict__ Ah_g,
                                                const u16* __restrict__ Al_g,
                                                const u16* __restrict__ Bh_g,
                                                const u16* __restrict__ Bl_g,
                                                const float* __restrict__ bq,
                                                const float* __restrict__ bk,
                                                const float* __restrict__ bv,
                                                const float* __restrict__ cosb,
                                                const float* __restrict__ sinb,
                                                u16* __restrict__ qh, u16* __restrict__ ql,
                                                u16* __restrict__ kh, u16* __restrict__ kl,
                                                u16* __restrict__ vb) {
  __shared__ u16 Ah[128][40], Al[128][40], Bh[128][40], Bl[128][40];
  int tid = threadIdx.x;
  int w = tid >> 6, l = tid & 63;
  int wr = w >> 1, wc = w & 1;
  int lg = l >> 4, lx = l & 15;
  int f = blockIdx.x;
  int xcd = f & 7, rr = f >> 3;        // rr 0..47
  int mt = xcd * 4 + (rr & 3);         // 0..31, m-slab pinned to XCD
  int nt = rr >> 2;                    // 0..11
  int m0 = mt * 128, n0 = nt * 128;
  int sr = tid >> 1, s16 = (tid & 1) * 16;
  const u16* Aph = Ah_g + (size_t)(m0 + sr) * 512;
  const u16* Apl = Al_g + (size_t)(m0 + sr) * 512;
  const u16* Bph = Bh_g + (size_t)(n0 + sr) * 512;
  const u16* Bpl = Bl_g + (size_t)(n0 + sr) * 512;
  f32x4 acc[4][4];
#pragma unroll
  for (int m = 0; m < 4; ++m)
#pragma unroll
    for (int n = 0; n < 4; ++n) acc[m][n] = (f32x4){0.f, 0.f, 0.f, 0.f};
  short8 ah0 = *(const short8*)&Aph[s16];
  short8 ah1 = *(const short8*)&Aph[s16 + 8];
  short8 al0 = *(const short8*)&Apl[s16];
  short8 al1 = *(const short8*)&Apl[s16 + 8];
  short8 bh0 = *(const short8*)&Bph[s16];
  short8 bh1 = *(const short8*)&Bph[s16 + 8];
  short8 bl0 = *(const short8*)&Bpl[s16];
  short8 bl1 = *(const short8*)&Bpl[s16 + 8];
  for (int k0 = 0; k0 < 512; k0 += 32) {
    __syncthreads();
    *(short8*)&Ah[sr][s16] = ah0; *(short8*)&Ah[sr][s16 + 8] = ah1;
    *(short8*)&Al[sr][s16] = al0; *(short8*)&Al[sr][s16 + 8] = al1;
    *(short8*)&Bh[sr][s16] = bh0; *(short8*)&Bh[sr][s16 + 8] = bh1;
    *(short8*)&Bl[sr][s16] = bl0; *(short8*)&Bl[sr][s16 + 8] = bl1;
    __syncthreads();
    if (k0 + 32 < 512) {
      int ko = k0 + 32 + s16;
      ah0 = *(const short8*)&Aph[ko]; ah1 = *(const short8*)&Aph[ko + 8];
      al0 = *(const short8*)&Apl[ko]; al1 = *(const short8*)&Apl[ko + 8];
      bh0 = *(const short8*)&Bph[ko]; bh1 = *(const short8*)&Bph[ko + 8];
      bl0 = *(const short8*)&Bpl[ko]; bl1 = *(const short8*)&Bpl[ko + 8];
    }
    short8 fah[4], fal[4], fbh[4], fbl[4];
#pragma unroll
    for (int m = 0; m < 4; ++m) {
      fah[m] = *(const short8*)&Ah[wr * 64 + m * 16 + lx][lg * 8];
      fal[m] = *(const short8*)&Al[wr * 64 + m * 16 + lx][lg * 8];
    }
#pragma unroll
    for (int n = 0; n < 4; ++n) {
      fbh[n] = *(const short8*)&Bh[wc * 64 + n * 16 + lx][lg * 8];
      fbl[n] = *(const short8*)&Bl[wc * 64 + n * 16 + lx][lg * 8];
    }
#pragma unroll
    for (int m = 0; m < 4; ++m)
#pragma unroll
      for (int n = 0; n < 4; ++n) {
        acc[m][n] = __builtin_amdgcn_mfma_f32_16x16x32_bf16(fah[m], fbh[n], acc[m][n], 0, 0, 0);
        acc[m][n] = __builtin_amdgcn_mfma_f32_16x16x32_bf16(fal[m], fbh[n], acc[m][n], 0, 0, 0);
        acc[m][n] = __builtin_amdgcn_mfma_f32_16x16x32_bf16(fah[m], fbl[n], acc[m][n], 0, 0, 0);
      }
  }
  // ---- epilogue ----
  int tcolbase = n0 + wc * 64;
  int tsel = tcolbase >> 9;             // 0=q, 1=k, 2=v
  int hbase = tcolbase & 511;
  const float* bias = (tsel == 0) ? bq : (tsel == 1) ? bk : bv;
  if (tsel == 2) {
#pragma unroll
    for (int m = 0; m < 4; ++m)
#pragma unroll
      for (int i = 0; i < 4; ++i) {
        int row = m0 + wr * 64 + m * 16 + lg * 4 + i;
#pragma unroll
        for (int n = 0; n < 4; ++n) {
          int col = hbase + n * 16 + lx;
          vb[(size_t)row * 512 + col] = f2bf(acc[m][n][i] + bias[col]);
        }
      }
  } else {
    u16* oh = tsel ? kh : qh;
    u16* ol = tsel ? kl : ql;
    float qsc = tsel ? 1.f : 0.125f;
#pragma unroll
    for (int m = 0; m < 4; ++m)
#pragma unroll
      for (int i = 0; i < 4; ++i) {
        int row = m0 + wr * 64 + m * 16 + lg * 4 + i;
        int s = row >> 1;
#pragma unroll
        for (int n = 0; n < 2; ++n) {
          int dln = n * 16 + lx;
          float c  = cosb[s * 64 + dln];
          float sn = sinb[s * 64 + dln];
          float a  = acc[m][n][i]     + bias[hbase + dln];
          float b2 = acc[m][n + 2][i] + bias[hbase + dln + 32];
          float ra = (a * c - b2 * sn) * qsc;
          float rb = (b2 * c + a * sn) * qsc;
          size_t ix = (size_t)row * 512 + hbase + dln;
          u16 rah = f2bf(ra);
          oh[ix] = rah; ol[ix] = f2bf(ra - bf2f(rah));
          u16 rbh = f2bf(rb);
          oh[ix + 32] = rbh; ol[ix + 32] = f2bf(rb - bf2f(rbh));
        }
      }
  }
}

// ---------------------------------------------------------------------------
// MFMA flash attention, KV-split=2, XCD-pinned (b,h,kvh) slabs, QT=128.
// KT=128: one softmax pass per 128 kv rows; PV in two 64-kv sub-chunks.
// ---------------------------------------------------------------------------
__global__ __launch_bounds__(512, 4) void attn_mfma2(const u16* __restrict__ qh,
                                                     const u16* __restrict__ ql,
                                                     const u16* __restrict__ kh,
                                                     const u16* __restrict__ kl,
                                                     const u16* __restrict__ vbuf,
                                                     u16* __restrict__ poh,
                                                     u16* __restrict__ pol,
                                                     float* __restrict__ pml) {
  __shared__ u16 Khi[128][72];
  __shared__ u16 Klo[128][72];
  __shared__ u16 Vt[64][136];          // [d][kv 0..127]
  __shared__ unsigned P2[8][16][32];   // per-wave P chunk (64 kv)
  int tid = threadIdx.x;
  int w = tid >> 6, l = tid & 63;      // w 0..7
  int lg = l >> 4, lx = l & 15;
  int f = blockIdx.x;                  // 0..511
  int xcd = f & 7, j = f >> 3;         // j 0..63
  int slab = xcd + 8 * (j & 3);        // 0..31 : all qt of a slab share an XCD
  int qt = j >> 2;                     // 0..15 (128-row q tiles)
  int bh = slab >> 1, kvh = slab & 1;
  int b = bh >> 3, h = bh & 7;

  short8 qfh[2], qfl[2];
  {
    int qrow = qt * 128 + w * 16 + lx;
    size_t qo = (size_t)(qrow * 2 + b) * 512 + h * 64 + lg * 8;
    qfh[0] = *(const short8*)&qh[qo];
    qfh[1] = *(const short8*)&qh[qo + 32];
    qfl[0] = *(const short8*)&ql[qo];
    qfl[1] = *(const short8*)&ql[qo + 32];
  }

  f32x4 o_acc[4];
#pragma unroll
  for (int dg = 0; dg < 4; ++dg) o_acc[dg] = (f32x4){0.f, 0.f, 0.f, 0.f};
  float m_run = -1e30f, l_run = 0.f;

  int kvr = tid >> 2, ds4 = (tid & 3) * 16;   // K: 128 rows x 64, 16 el/thread
  int kvc = tid & 127, dsg = (tid >> 7) * 16; // V: transpose, 16 el/thread
  int psw = (lx & 7) << 2;                    // P2 bank swizzle

  short8 rkh0, rkh1, rkl0, rkl1, rv0, rv1;
  {
    int t0 = kvh * 1024;
    size_t ko = (size_t)((t0 + kvr) * 2 + b) * 512 + h * 64 + ds4;
    rkh0 = *(const short8*)&kh[ko]; rkh1 = *(const short8*)&kh[ko + 8];
    rkl0 = *(const short8*)&kl[ko]; rkl1 = *(const short8*)&kl[ko + 8];
    size_t vo = (size_t)((t0 + kvc) * 2 + b) * 512 + h * 64 + dsg;
    rv0 = *(const short8*)&vbuf[vo]; rv1 = *(const short8*)&vbuf[vo + 8];
  }

  for (int it = 0; it < 8; ++it) {
    __syncthreads();
    *(short8*)&Khi[kvr][ds4]     = rkh0;
    *(short8*)&Khi[kvr][ds4 + 8] = rkh1;
    *(short8*)&Klo[kvr][ds4]     = rkl0;
    *(short8*)&Klo[kvr][ds4 + 8] = rkl1;
#pragma unroll
    for (int c = 0; c < 8; ++c) {
      Vt[dsg + c][kvc]     = (u16)rv0[c];
      Vt[dsg + 8 + c][kvc] = (u16)rv1[c];
    }
    __syncthreads();
    if (it + 1 < 8) {
      int t0 = kvh * 1024 + (it + 1) * 128;
      size_t ko = (size_t)((t0 + kvr) * 2 + b) * 512 + h * 64 + ds4;
      rkh0 = *(const short8*)&kh[ko]; rkh1 = *(const short8*)&kh[ko + 8];
      rkl0 = *(const short8*)&kl[ko]; rkl1 = *(const short8*)&kl[ko + 8];
      size_t vo = (size_t)((t0 + kvc) * 2 + b) * 512 + h * 64 + dsg;
      rv0 = *(const short8*)&vbuf[vo]; rv1 = *(const short8*)&vbuf[vo + 8];
    }

    // ---- QK^T, swapped: D[kv][q], kv = 16cg+4lg+i (cg 0..7) ----
    f32x4 sc[8];
#pragma unroll
    for (int cg = 0; cg < 8; ++cg) {
      short8 kf0 = *(const short8*)&Khi[cg * 16 + lx][lg * 8];
      short8 kf1 = *(const short8*)&Khi[cg * 16 + lx][32 + lg * 8];
      short8 kg0 = *(const short8*)&Klo[cg * 16 + lx][lg * 8];
      short8 kg1 = *(const short8*)&Klo[cg * 16 + lx][32 + lg * 8];
      f32x4 a = (f32x4){0.f, 0.f, 0.f, 0.f};
      a = __builtin_amdgcn_mfma_f32_16x16x32_bf16(kf0, qfh[0], a, 0, 0, 0);
      a = __builtin_amdgcn_mfma_f32_16x16x32_bf16(kf1, qfh[1], a, 0, 0, 0);
      a = __builtin_amdgcn_mfma_f32_16x16x32_bf16(kf0, qfl[0], a, 0, 0, 0);
      a = __builtin_amdgcn_mfma_f32_16x16x32_bf16(kf1, qfl[1], a, 0, 0, 0);
      a = __builtin_amdgcn_mfma_f32_16x16x32_bf16(kg0, qfh[0], a, 0, 0, 0);
      a = __builtin_amdgcn_mfma_f32_16x16x32_bf16(kg1, qfh[1], a, 0, 0, 0);
      sc[cg] = a;
    }

    // ---- ONE in-register softmax over all 128 kv for q = lx ----
    float tm = sc[0][0];
#pragma unroll
    for (int cg = 0; cg < 8; ++cg)
#pragma unroll
      for (int i = 0; i < 4; ++i) tm = fmaxf(tm, sc[cg][i]);
    tm = fmaxf(tm, __shfl_xor(tm, 16));
    tm = fmaxf(tm, __shfl_xor(tm, 32));
    float mn = fmaxf(m_run, tm);
    float corr = __expf(m_run - mn);
    m_run = mn;
    float ts = 0.f;
#pragma unroll
    for (int cg = 0; cg < 8; ++cg)
#pragma unroll
      for (int i = 0; i < 4; ++i) {
        float pv = __expf(sc[cg][i] - mn);
        sc[cg][i] = pv;
        ts += pv;
      }
    ts += __shfl_xor(ts, 16);
    ts += __shfl_xor(ts, 32);
    l_run = l_run * corr + ts;
#pragma unroll
    for (int dg = 0; dg < 4; ++dg) o_acc[dg] *= corr;

    // ---- PV in two 64-kv chunks, reusing P2 (wave-local) ----
#pragma unroll
    for (int ch = 0; ch < 2; ++ch) {
#pragma unroll
      for (int cg = 0; cg < 4; ++cg)
#pragma unroll
        for (int t = 0; t < 2; ++t) {
          const f32x4& s4 = sc[4 * ch + cg];
          unsigned dw = (unsigned)f2bf(s4[2 * t]) |
                        ((unsigned)f2bf(s4[2 * t + 1]) << 16);
          P2[w][lx][(8 * cg + 2 * lg + t) ^ psw] = dw;
        }
      short8 pf0 = *(const short8*)&P2[w][lx][(4 * lg) ^ psw];
      short8 pf1 = *(const short8*)&P2[w][lx][(16 + 4 * lg) ^ psw];
#pragma unroll
      for (int dg = 0; dg < 4; ++dg) {
        short8 v0 = *(const short8*)&Vt[dg * 16 + lx][ch * 64 + lg * 8];
        short8 v1 = *(const short8*)&Vt[dg * 16 + lx][ch * 64 + 32 + lg * 8];
        o_acc[dg] = __builtin_amdgcn_mfma_f32_16x16x32_bf16(v0, pf0, o_acc[dg], 0, 0, 0);
        o_acc[dg] = __builtin_amdgcn_mfma_f32_16x16x32_bf16(v1, pf1, o_acc[dg], 0, 0, 0);
      }
    }
  }

  // ---- epilogue: lane holds ctx^T[d=16dg+4lg+i][q=lx] ----
  {
    int qrow = qt * 128 + w * 16 + lx;
    int row2 = qrow * 2 + b;
    size_t base = (size_t)kvh * ((size_t)N_ * D_) + (size_t)row2 * 512 + h * 64;
#pragma unroll
    for (int dg = 0; dg < 4; ++dg)
#pragma unroll
      for (int i = 0; i < 4; ++i) {
        int d = dg * 16 + 4 * lg + i;
        float val = o_acc[dg][i];
        u16 hi = f2bf(val);
        poh[base + d] = hi;
        pol[base + d] = f2bf(val - bf2f(hi));
      }
    if (lg == 0) {
      int u = row2 * 8 + h;
      pml[(size_t)kvh * 65536 + u * 2 + 0] = m_run;
      pml[(size_t)kvh * 65536 + u * 2 + 1] = l_run;
    }
  }
}

// ---------------------------------------------------------------------------
// Wo projection with FUSED KV-half merge in A-staging.
// A[r][c] = ((poh0+pol0)*e0 + (poh1+pol1)*e1) * inv  (identical to old merge)
// split hi/lo in staging. M=4096, N=512, K=512, f32 out.
// Flat XCD-pinned grid (128 = 8 xcd x 4 m x 4 n).
// ---------------------------------------------------------------------------
__global__ __launch_bounds__(256) void wo_mfma(const u16* __restrict__ poh,
                                               const u16* __restrict__ pol,
                                               const float* __restrict__ pml,
                                               const u16* __restrict__ Bh_g,
                                               const u16* __restrict__ Bl_g,
                                               const float* __restrict__ bias,
                                               float* __restrict__ C) {
  __shared__ u16 Ah[128][40], Al[128][40], Bh[128][40], Bl[128][40];
  int tid = threadIdx.x;
  int w = tid >> 6, l = tid & 63;
  int wr = w >> 1, wc = w & 1;
  int lg = l >> 4, lx = l & 15;
  int f = blockIdx.x;
  int xcd = f & 7, rr = f >> 3;        // rr 0..15
  int m0 = (xcd * 4 + (rr & 3)) * 128;
  int n0 = (rr >> 2) * 128;
  int sr = tid >> 1, s16 = (tid & 1) * 16;
  const size_t PO1 = (size_t)N_ * D_;
  size_t aoff = (size_t)(m0 + sr) * 512;
  const u16* P0h = poh + aoff;
  const u16* P0l = pol + aoff;
  const u16* P1h = poh + PO1 + aoff;
  const u16* P1l = pol + PO1 + aoff;
  int urow = (m0 + sr) * 8;
  const u16* Bph = Bh_g + (size_t)(n0 + sr) * 512;
  const u16* Bpl = Bl_g + (size_t)(n0 + sr) * 512;
  f32x4 acc[4][4];
#pragma unroll
  for (int m = 0; m < 4; ++m)
#pragma unroll
    for (int n = 0; n < 4; ++n) acc[m][n] = (f32x4){0.f, 0.f, 0.f, 0.f};
  // prefetch k0 = 0
  short8 r0h0 = *(const short8*)&P0h[s16];
  short8 r0h1 = *(const short8*)&P0h[s16 + 8];
  short8 r0l0 = *(const short8*)&P0l[s16];
  short8 r0l1 = *(const short8*)&P0l[s16 + 8];
  short8 r1h0 = *(const short8*)&P1h[s16];
  short8 r1h1 = *(const short8*)&P1h[s16 + 8];
  short8 r1l0 = *(const short8*)&P1l[s16];
  short8 r1l1 = *(const short8*)&P1l[s16 + 8];
  int hh = s16 >> 6;                    // head of this segment (0 at k0=0)
  float m0v = pml[(urow + hh) * 2], l0v = pml[(urow + hh) * 2 + 1];
  float m1v = pml[65536 + (urow + hh) * 2], l1v = pml[65536 + (urow + hh) * 2 + 1];
  short8 bh0 = *(const short8*)&Bph[s16];
  short8 bh1 = *(const short8*)&Bph[s16 + 8];
  short8 bl0 = *(const short8*)&Bpl[s16];
  short8 bl1 = *(const short8*)&Bpl[s16 + 8];
  for (int k0 = 0; k0 < 512; k0 += 32) {
    __syncthreads();
    // merge + split the prefetched A segment
    {
      float mm = fmaxf(m0v, m1v);
      float e0 = __expf(m0v - mm), e1 = __expf(m1v - mm);
      float inv = 1.f / (l0v * e0 + l1v * e1);
      short8 oh0, ol0, oh1, ol1;
#pragma unroll
      for (int jj = 0; jj < 8; ++jj) {
        float v0 = bf2f((u16)r0h0[jj]) + bf2f((u16)r0l0[jj]);
        float v1 = bf2f((u16)r1h0[jj]) + bf2f((u16)r1l0[jj]);
        float val = (v0 * e0 + v1 * e1) * inv;
        u16 hi = f2bf(val);
        oh0[jj] = (short)hi;
        ol0[jj] = (short)f2bf(val - bf2f(hi));
        float w0 = bf2f((u16)r0h1[jj]) + bf2f((u16)r0l1[jj]);
        float w1 = bf2f((u16)r1h1[jj]) + bf2f((u16)r1l1[jj]);
        float wal = (w0 * e0 + w1 * e1) * inv;
        u16 whi = f2bf(wal);
        oh1[jj] = (short)whi;
        ol1[jj] = (short)f2bf(wal - bf2f(whi));
      }
      *(short8*)&Ah[sr][s16] = oh0; *(short8*)&Ah[sr][s16 + 8] = oh1;
      *(short8*)&Al[sr][s16] = ol0; *(short8*)&Al[sr][s16 + 8] = ol1;
    }
    *(short8*)&Bh[sr][s16] = bh0; *(short8*)&Bh[sr][s16 + 8] = bh1;
    *(short8*)&Bl[sr][s16] = bl0; *(short8*)&Bl[sr][s16 + 8] = bl1;
    __syncthreads();
    if (k0 + 32 < 512) {
      int ko = k0 + 32 + s16;
      r0h0 = *(const short8*)&P0h[ko]; r0h1 = *(const short8*)&P0h[ko + 8];
      r0l0 = *(const short8*)&P0l[ko]; r0l1 = *(const short8*)&P0l[ko + 8];
      r1h0 = *(const short8*)&P1h[ko]; r1h1 = *(const short8*)&P1h[ko + 8];
      r1l0 = *(const short8*)&P1l[ko]; r1l1 = *(const short8*)&P1l[ko + 8];
      int h2 = ko >> 6;
      m0v = pml[(urow + h2) * 2]; l0v = pml[(urow + h2) * 2 + 1];
      m1v = pml[65536 + (urow + h2) * 2]; l1v = pml[65536 + (urow + h2) * 2 + 1];
      bh0 = *(const short8*)&Bph[ko]; bh1 = *(const short8*)&Bph[ko + 8];
      bl0 = *(const short8*)&Bpl[ko]; bl1 = *(const short8*)&Bpl[ko + 8];
    }
    short8 fah[4], fal[4], fbh[4], fbl[4];
#pragma unroll
    for (int m = 0; m < 4; ++m) {
      fah[m] = *(const short8*)&Ah[wr * 64 + m * 16 + lx][lg * 8];
      fal[m] = *(const short8*)&Al[wr * 64 + m * 16 + lx][lg * 8];
    }
#pragma unroll
    for (int n = 0; n < 4; ++n) {
      fbh[n] = *(const short8*)&Bh[wc * 64 + n * 16 + lx][lg * 8];
      fbl[n] = *(const short8*)&Bl[wc * 64 + n * 16 + lx][lg * 8];
    }
#pragma unroll
    for (int m = 0; m < 4; ++m)
#pragma unroll
      for (int n = 0; n < 4; ++n) {
        acc[m][n] = __builtin_amdgcn_mfma_f32_16x16x32_bf16(fah[m], fbh[n], acc[m][n], 0, 0, 0);
        acc[m][n] = __builtin_amdgcn_mfma_f32_16x16x32_bf16(fal[m], fbh[n], acc[m][n], 0, 0, 0);
        acc[m][n] = __builtin_amdgcn_mfma_f32_16x16x32_bf16(fah[m], fbl[n], acc[m][n], 0, 0, 0);
      }
  }
#pragma unroll
  for (int m = 0; m < 4; ++m)
#pragma unroll
    for (int i = 0; i < 4; ++i) {
      int row = m0 + wr * 64 + m * 16 + lg * 4 + i;
#pragma unroll
      for (int n = 0; n < 4; ++n) {
        int col = n0 + wc * 64 + n * 16 + lx;
        C[(size_t)row * 512 + col] = acc[m][n][i] + bias[col];
      }
    }
}

// ---------------------------------------------------------------------------
// LayerNorm with residual + bf16 copy + FUSED gate top-2.
// ---------------------------------------------------------------------------
__global__ __launch_bounds__(256) void ln_res_gate(const float* __restrict__ a,
                                                   const float* __restrict__ b,
                                                   const float* __restrict__ g,
                                                   const float* __restrict__ beta,
                                                   const float* __restrict__ Wg,
                                                   float* __restrict__ out,
                                                   u16* __restrict__ obf,
                                                   float* __restrict__ gp,
                                                   int* __restrict__ tope) {
  int n = blockIdx.x * 4 + (threadIdx.x >> 6);
  int lane = threadIdx.x & 63;
  float v[8];
  float s = 0.f;
#pragma unroll
  for (int i = 0; i < 8; ++i) {
    int d = lane + 64 * i;
    v[i] = a[(size_t)n * D_ + d] + b[(size_t)n * D_ + d];
    s += v[i];
  }
#pragma unroll
  for (int m = 32; m; m >>= 1) s += __shfl_xor(s, m);
  float mean = s * (1.f / D_);
  float s2 = 0.f;
#pragma unroll
  for (int i = 0; i < 8; ++i) { float t = v[i] - mean; s2 += t * t; }
#pragma unroll
  for (int m = 32; m; m >>= 1) s2 += __shfl_xor(s2, m);
  float r = rsqrtf(s2 * (1.f / D_) + 1e-5f);
  float p[E_] = {};
#pragma unroll
  for (int i = 0; i < 8; ++i) {
    int d = lane + 64 * i;
    float val = (v[i] - mean) * r * g[d] + beta[d];
    out[(size_t)n * D_ + d] = val;
    obf[(size_t)n * D_ + d] = f2bf(val);
    const float* wr = &Wg[(size_t)d * E_];
#pragma unroll
    for (int e = 0; e < E_; ++e) p[e] += val * wr[e];
  }
#pragma unroll
  for (int e = 0; e < E_; ++e)
#pragma unroll
    for (int m = 32; m; m >>= 1) p[e] += __shfl_xor(p[e], m);
  if (lane == 0) {
    float mx = p[0];
#pragma unroll
    for (int e = 1; e < E_; ++e) mx = fmaxf(mx, p[e]);
    float q[E_];
#pragma unroll
    for (int e = 0; e < E_; ++e) q[e] = expf(p[e] - mx);
    int e1 = 0;
#pragma unroll
    for (int e = 1; e < E_; ++e) if (q[e] > q[e1]) e1 = e;
    int e2 = (e1 == 0) ? 1 : 0;
#pragma unroll
    for (int e = 0; e < E_; ++e) if (e != e1 && q[e] > q[e2]) e2 = e;
    float denom = q[e1] + q[e2];
    gp[n * 2] = q[e1] / denom;
    gp[n * 2 + 1] = q[e2] / denom;
    tope[n] = e1 | (e2 << 8);
  }
}

__global__ __launch_bounds__(256) void ln2_final(const float* __restrict__ x,
                                                 const u16* __restrict__ mp,
                                                 const float* __restrict__ g,
                                                 const float* __restrict__ beta,
                                                 float* __restrict__ out) {
  int n = blockIdx.x * 4 + (threadIdx.x >> 6);
  int lane = threadIdx.x & 63;
  float v[8];
  float s = 0.f;
#pragma unroll
  for (int i = 0; i < 8; ++i) {
    int d = lane + 64 * i;
    v[i] = x[(size_t)n * D_ + d] + bf2f(mp[(size_t)(2 * n) * D_ + d]) +
           bf2f(mp[(size_t)(2 * n + 1) * D_ + d]);
    s += v[i];
  }
#pragma unroll
  for (int m = 32; m; m >>= 1) s += __shfl_xor(s, m);
  float mean = s * (1.f / D_);
  float s2 = 0.f;
#pragma unroll
  for (int i = 0; i < 8; ++i) { float t = v[i] - mean; s2 += t * t; }
#pragma unroll
  for (int m = 32; m; m >>= 1) s2 += __shfl_xor(s2, m);
  float r = rsqrtf(s2 * (1.f / D_) + 1e-5f);
#pragma unroll
  for (int i = 0; i < 8; ++i) {
    int d = lane + 64 * i;
    out[(size_t)n * D_ + d] = (v[i] - mean) * r * g[d] + beta[d];
  }
}

// ---------------------------------------------------------------------------
// Gate phase B: per-expert ordered compaction. One block per expert.
// ---------------------------------------------------------------------------
__global__ __launch_bounds__(256) void route_build(const int* __restrict__ tope,
                                                   int* __restrict__ cnt,
                                                   int* __restrict__ lst) {
  int e = blockIdx.x;
  __shared__ int wsum[4];
  __shared__ int basem;
  int tid = threadIdx.x;
  int w = tid >> 6, lane = tid & 63;
  if (tid == 0) basem = 0;
  __syncthreads();
  for (int c0 = 0; c0 < N_; c0 += 256) {
    int n = c0 + tid;
    int te = tope[n];
    int e1 = te & 0xff, e2 = (te >> 8) & 0xff;
    bool m2 = (e2 == e);
    bool flag = (e1 == e) || m2;
    unsigned long long mask = __ballot(flag);
    int wpre = __popcll(mask & ((1ull << lane) - 1ull));
    if (lane == 0) wsum[w] = __popcll(mask);
    __syncthreads();
    int woff = 0;
    for (int i = 0; i < w; ++i) woff += wsum[i];
    int total = wsum[0] + wsum[1] + wsum[2] + wsum[3];
    if (flag) lst[e * N_ + basem + woff + wpre] = n * 2 + (m2 ? 1 : 0);
    __syncthreads();
    if (tid == 0) basem += total;
    __syncthreads();
  }
  if (tid == 0) cnt[e] = basem;
}

// ---------------------------------------------------------------------------
// bf16 MFMA MoE GEMM, 64x128 tile, BK=32, 4 waves (each 64x32 out).
// Flat grid, expert = blockIdx & 7 -> expert pinned to one XCD.
// ---------------------------------------------------------------------------
template <int MODE>
__global__ __launch_bounds__(256) void moe_mfma(const u16* __restrict__ Abase,
                                                const u16* __restrict__ Wt,
                                                const float* __restrict__ bias,
                                                const float* __restrict__ gp,
                                                u16* __restrict__ outp,
                                                const int* __restrict__ cnt,
                                                const int* __restrict__ lst) {
  constexpr int K  = MODE ? 1024 : 512;
  constexpr int Nn = MODE ? 512 : 1024;
  constexpr int NT = Nn / 128;
  constexpr int NI = K / 32;
  int fidx = blockIdx.x;
  int e = fidx & 7;
  int r = fidx >> 3;
  int nt = r % NT;
  int mt = r / NT;
  int c = cnt[e];
  int m0 = mt * 64;
  if (m0 >= c) return;
  int off = 0;
#pragma unroll
  for (int i = 0; i < E_; ++i) if (i < e) off += cnt[i];
  int n0 = nt * 128;
  __shared__ u16 As[64][40];
  __shared__ u16 Bs[128][40];
  int tid = threadIdx.x;
  int w = tid >> 6, l = tid & 63;
  int lg = l >> 4, lx = l & 15;
  int arow = tid >> 2, aseg = (tid & 3) * 8;
  int brow = tid >> 1, bseg = (tid & 1) * 16;
  int ar = m0 + arow; if (ar >= c) ar = c - 1;
  const u16* Ap;
  if (MODE == 0) Ap = Abase + (size_t)(lst[e * N_ + ar] >> 1) * 512 + aseg;
  else           Ap = Abase + (size_t)(off + ar) * 1024 + aseg;
  const u16* Bp = Wt + (size_t)e * K * Nn + (size_t)(n0 + brow) * K + bseg;

  f32x4 acc[4][2];
#pragma unroll
  for (int m = 0; m < 4; ++m)
#pragma unroll
    for (int n = 0; n < 2; ++n) acc[m][n] = (f32x4){0.f, 0.f, 0.f, 0.f};

  short8 pa  = *(const short8*)&Ap[0];
  short8 pb0 = *(const short8*)&Bp[0];
  short8 pb1 = *(const short8*)&Bp[8];
  for (int kk = 0; kk < NI; ++kk) {
    __syncthreads();
    *(short8*)&As[arow][aseg] = pa;
    *(short8*)&Bs[brow][bseg] = pb0;
    *(short8*)&Bs[brow][bseg + 8] = pb1;
    __syncthreads();
    if (kk + 1 < NI) {
      int ko = (kk + 1) * 32;
      pa  = *(const short8*)&Ap[ko];
      pb0 = *(const short8*)&Bp[ko];
      pb1 = *(const short8*)&Bp[ko + 8];
    }
    short8 af[4], bf[2];
#pragma unroll
    for (int m = 0; m < 4; ++m)
      af[m] = *(const short8*)&As[m * 16 + lx][lg * 8];
#pragma unroll
    for (int n = 0; n < 2; ++n)
      bf[n] = *(const short8*)&Bs[w * 32 + n * 16 + lx][lg * 8];
#pragma unroll
    for (int m = 0; m < 4; ++m)
#pragma unroll
      for (int n = 0; n < 2; ++n)
        acc[m][n] = __builtin_amdgcn_mfma_f32_16x16x32_bf16(af[m], bf[n], acc[m][n], 0, 0, 0);
  }
#pragma unroll
  for (int m = 0; m < 4; ++m)
#pragma unroll
    for (int i = 0; i < 4; ++i) {
      int rr = m0 + m * 16 + lg * 4 + i;
      if (rr < c) {
#pragma unroll
        for (int n = 0; n < 2; ++n) {
          int col = n0 + w * 32 + n * 16 + lx;
          float val = acc[m][n][i] + bias[e * Nn + col];
          if (MODE == 0) {
            outp[(size_t)(off + rr) * 1024 + col] = f2bf(fmaxf(val, 0.f));
          } else {
            int p = lst[e * N_ + rr];
            outp[(size_t)p * 512 + col] = f2bf(gp[p] * val);
          }
        }
      }
    }
}

// ---------------------------------------------------------------------------
extern "C" void kernel_launch(void* const* d_in, const int* in_sizes, int n_in,
                              void* d_out, int out_size, void* d_ws, size_t ws_size,
                              hipStream_t stream) {
  const float* src  = (const float*)d_in[0];
  const float* cosb = (const float*)d_in[1];
  const float* sinb = (const float*)d_in[2];
  const float* Wq   = (const float*)d_in[3];
  const float* bq   = (const float*)d_in[4];
  const float* Wk   = (const float*)d_in[5];
  const float* bk   = (const float*)d_in[6];
  const float* Wv   = (const float*)d_in[7];
  const float* bv   = (const float*)d_in[8];
  const float* Wo   = (const float*)d_in[9];
  const float* bo   = (const float*)d_in[10];
  const float* ln1g = (const float*)d_in[11];
  const float* ln1b = (const float*)d_in[12];
  const float* ln2g = (const float*)d_in[13];
  const float* ln2b = (const float*)d_in[14];
  const float* Wg   = (const float*)d_in[15];
  const float* W1   = (const float*)d_in[16];
  const float* B1   = (const float*)d_in[17];
  const float* W2   = (const float*)d_in[18];
  const float* B2   = (const float*)d_in[19];
  float* out = (float*)d_out;
  char* wsb = (char*)d_ws;

  const size_t MB1 = 1u << 20;
  // Layout: aob moved to [0,8M) (ex-ch/cl region) since wo now READS poh/pol.
  u16* sh   = (u16*)(wsb + 0 * MB1);      // src hi  [0,4M)  src_split->qkv
  u16* sl   = (u16*)(wsb + 4 * MB1);      // src lo  [4,8M)
  float* aob = (float*)(wsb + 0 * MB1);   // [0,8M)  wo->lnrg (sh/sl dead after qkv)
  u16* qhb  = (u16*)(wsb + 8 * MB1);      // [8,12M)          ; later hbf part
  u16* qlb  = (u16*)(wsb + 12 * MB1);
  u16* khb  = (u16*)(wsb + 16 * MB1);
  u16* klb  = (u16*)(wsb + 20 * MB1);
  u16* vbuf = (u16*)(wsb + 24 * MB1);     // [24,28M)
  u16* poh  = (u16*)(wsb + 28 * MB1);     // [28,36M) attn->wo ; later W2t
  u16* pol  = (u16*)(wsb + 36 * MB1);     // [36,44M) attn->wo ; later xb f32
  float* pml = (float*)(wsb + 44 * MB1);  // [44,44.5M) attn->wo ; later xbf
  float* xb  = (float*)(wsb + 36 * MB1);  // [36,44M) lnrg->ln2 (pol dead after wo)
  u16* xbf   = (u16*)(wsb + 44 * MB1);    // [44,48M) lnrg->moe1 (pml dead after wo)
  u16* Wqkv_hi = (u16*)(wsb + 48 * MB1);              // 1.5MB
  u16* Wqkv_lo = (u16*)(wsb + 48 * MB1 + 1572864);    // 1.5MB
  u16* Wo_hi   = (u16*)(wsb + 48 * MB1 + 3145728);    // 0.5MB
  u16* Wo_lo   = (u16*)(wsb + 48 * MB1 + 3670016);    // 0.5MB
  u16* W1t     = (u16*)(wsb + 52 * MB1);  // [52,60M)
  u16* W2t     = (u16*)(wsb + 28 * MB1);  // [28,36M) — written after ln_res_gate (poh dead)
  float* gpb   = (float*)(wsb + 60 * MB1);                 // 32 KB
  int* cnt     = (int*)(wsb + 60 * MB1 + 32768);           // 64 B
  int* lst     = (int*)(wsb + 60 * MB1 + 32768 + 64);      // 128 KB
  int* tope    = (int*)(wsb + 60 * MB1 + 32768 + 64 + 131072);  // 16 KB
  u16* hbf = (u16*)(wsb + 8 * MB1);       // [8,24M) aliases q/k (dead after attn)
  u16* mp  = (u16*)(wsb + 0 * MB1);       // [0,8M)  aliases aob (dead after lnrg)

  dim3 blk(256);
  src_split<<<dim3(1024), blk, 0, stream>>>(src, sh, sl);
  // All 4 weight splits in ONE launch
  wsplit_all<<<dim3(8, 8, 4), blk, 0, stream>>>(Wq, Wk, Wv, Wo,
                                                Wqkv_hi, Wqkv_lo, Wo_hi, Wo_lo);
  // QKV + RoPE fused (split-bf16, f32-grade), XCD-pinned flat grid
  qkv_mfma<<<dim3(384), blk, 0, stream>>>(sh, sl, Wqkv_hi, Wqkv_lo, bq, bk, bv,
                                          cosb, sinb, qhb, qlb, khb, klb, vbuf);
  // Attention, KV-split=2, XCD-pinned slabs, QT=128, KT=128
  attn_mfma2<<<dim3(512), dim3(512), 0, stream>>>(qhb, qlb, khb, klb, vbuf, poh, pol, pml);
  // Wo projection with FUSED KV-half merge (merge_attn2 eliminated)
  wo_mfma<<<dim3(128), blk, 0, stream>>>(poh, pol, pml, Wo_hi, Wo_lo, bo, aob);
  // LN1 + fused gate top-2
  ln_res_gate<<<dim3(1024), blk, 0, stream>>>(src, aob, ln1g, ln1b, Wg, xb, xbf, gpb, tope);
  // MoE weight transposes — W1+W2 in ONE launch
  wtrans_all<<<dim3(16, 16, 16), blk, 0, stream>>>(W1, W2, W1t, W2t);
  // Ordered routing
  route_build<<<dim3(8), blk, 0, stream>>>(tope, cnt, lst);
  // Sparse MoE expert GEMMs — 64x128 tiles, expert pinned to XCD
  moe_mfma<0><<<dim3(8 * 8 * 64), blk, 0, stream>>>(xbf, W1t, B1, gpb, hbf, cnt, lst);
  moe_mfma<1><<<dim3(8 * 4 * 64), blk, 0, stream>>>(hbf, W2t, B2, gpb, mp, cnt, lst);
  ln2_final<<<dim3(1024), blk, 0, stream>>>(xb, mp, ln2g, ln2b, out);
}

// Round 18
// 208.873 us; speedup vs baseline: 1.0468x; 1.0468x over previous
//
#include <hip/hip_runtime.h>
#include <math.h>

// Shapes (fixed)
#define S_  2048
#define B_  2
#define D_  512
#define H_  8
#define DH_ 64
#define E_  8
#define F_  1024
#define N_  4096   // S_*B_
#define NPAIR_ 8192

typedef __attribute__((ext_vector_type(4))) float f32x4;
typedef __attribute__((ext_vector_type(8))) short short8;
typedef unsigned short u16;

__device__ __forceinline__ u16 f2bf(float f) {
  unsigned u = __builtin_bit_cast(unsigned, f);
  u += 0x7fffu + ((u >> 16) & 1u);
  return (u16)(u >> 16);
}
__device__ __forceinline__ float bf2f(u16 h) {
  unsigned u = ((unsigned)h) << 16;
  return __builtin_bit_cast(float, u);
}

// ---------------------------------------------------------------------------
// Weight transpose + split (device body): Whi/Wlo[n][k] = split(W[k][n]).
// ---------------------------------------------------------------------------
__device__ __forceinline__ void wsplit_body(const float* __restrict__ W,
                                            u16* __restrict__ Whi,
                                            u16* __restrict__ Wlo,
                                            int Nn, int K, int kb, int nb) {
  __shared__ u16 Th[64][72];
  __shared__ u16 Tl[64][72];
  int r = threadIdx.x >> 2, c0 = (threadIdx.x & 3) * 16;
  const float* wp = &W[(size_t)(kb + r) * Nn + nb + c0];
#pragma unroll
  for (int c = 0; c < 16; c += 4) {
    float4 t = *(const float4*)&wp[c];
    float f[4] = {t.x, t.y, t.z, t.w};
#pragma unroll
    for (int j = 0; j < 4; ++j) {
      u16 a = f2bf(f[j]);
      Th[r][c0 + c + j] = a;
      Tl[r][c0 + c + j] = f2bf(f[j] - bf2f(a));
    }
  }
  __syncthreads();
  short8 h0, h1, l0, l1;
#pragma unroll
  for (int j = 0; j < 8; ++j) {
    h0[j] = (short)Th[c0 + j][r];     h1[j] = (short)Th[c0 + 8 + j][r];
    l0[j] = (short)Tl[c0 + j][r];     l1[j] = (short)Tl[c0 + 8 + j][r];
  }
  size_t ob = (size_t)(nb + r) * K + kb + c0;
  *(short8*)&Whi[ob] = h0;  *(short8*)&Whi[ob + 8] = h1;
  *(short8*)&Wlo[ob] = l0;  *(short8*)&Wlo[ob + 8] = l1;
}

// One launch: Wq/Wk/Wv/Wo splits (z<4) + src split (z>=4). grid (8,8,20).
__global__ __launch_bounds__(256) void wsplit_all(const float* __restrict__ Wq,
                                                  const float* __restrict__ Wk,
                                                  const float* __restrict__ Wv,
                                                  const float* __restrict__ Wo,
                                                  const float* __restrict__ src,
                                                  u16* __restrict__ Wqkv_hi,
                                                  u16* __restrict__ Wqkv_lo,
                                                  u16* __restrict__ Wo_hi,
                                                  u16* __restrict__ Wo_lo,
                                                  u16* __restrict__ sh,
                                                  u16* __restrict__ sl) {
  int z = blockIdx.z;
  if (z < 4) {
    const float* W = (z == 0) ? Wq : (z == 1) ? Wk : (z == 2) ? Wv : Wo;
    u16* Whi = (z == 3) ? Wo_hi : Wqkv_hi + (size_t)z * 512 * 512;
    u16* Wlo = (z == 3) ? Wo_lo : Wqkv_lo + (size_t)z * 512 * 512;
    wsplit_body(W, Whi, Wlo, 512, 512, blockIdx.y * 64, blockIdx.x * 64);
  } else {
    // src -> split bf16, 64-block chunk per z-slice
    int idx = (z - 4) * 64 + blockIdx.y * 8 + blockIdx.x;
    size_t i = ((size_t)idx * 256 + threadIdx.x) * 8;
    float f[8];
    *(float4*)&f[0] = *(const float4*)&src[i];
    *(float4*)&f[4] = *(const float4*)&src[i + 4];
    short8 h, l;
#pragma unroll
    for (int j = 0; j < 8; ++j) {
      u16 a = f2bf(f[j]);
      h[j] = (short)a;
      l[j] = (short)f2bf(f[j] - bf2f(a));
    }
    *(short8*)&sh[i] = h;
    *(short8*)&sl[i] = l;
  }
}

// ---------------------------------------------------------------------------
// MoE weight transpose (W1+W2) + route_build in ONE launch.
// grid (16,16,17): z<8 W1 expert z; z<16 W2 expert z-8; z==16 route (8 blocks).
// ---------------------------------------------------------------------------
__global__ __launch_bounds__(256) void wtrans_all(const float* __restrict__ W1,
                                                  const float* __restrict__ W2,
                                                  u16* __restrict__ W1t,
                                                  u16* __restrict__ W2t,
                                                  const int* __restrict__ tope,
                                                  int* __restrict__ cnt,
                                                  int* __restrict__ lst) {
  int z = blockIdx.z;
  __shared__ u16 T[64][72];
  __shared__ int wsum[4];
  __shared__ int basem;
  if (z == 16) {
    // ---- route_build: per-expert ordered compaction ----
    if (blockIdx.x >= 8 || blockIdx.y != 0) return;
    int e = blockIdx.x;
    int tid = threadIdx.x;
    int w = tid >> 6, lane = tid & 63;
    if (tid == 0) basem = 0;
    __syncthreads();
    for (int c0 = 0; c0 < N_; c0 += 256) {
      int n = c0 + tid;
      int te = tope[n];
      int e1 = te & 0xff, e2 = (te >> 8) & 0xff;
      bool m2 = (e2 == e);
      bool flag = (e1 == e) || m2;
      unsigned long long mask = __ballot(flag);
      int wpre = __popcll(mask & ((1ull << lane) - 1ull));
      if (lane == 0) wsum[w] = __popcll(mask);
      __syncthreads();
      int woff = 0;
      for (int i = 0; i < w; ++i) woff += wsum[i];
      int total = wsum[0] + wsum[1] + wsum[2] + wsum[3];
      if (flag) lst[e * N_ + basem + woff + wpre] = n * 2 + (m2 ? 1 : 0);
      __syncthreads();
      if (tid == 0) basem += total;
      __syncthreads();
    }
    if (tid == 0) cnt[e] = basem;
    return;
  }
  const float* W;
  u16* Wt;
  int K, Nn, e;
  if (z < 8) {
    if (blockIdx.y >= 8) return;
    W = W1; Wt = W1t; K = 512; Nn = 1024; e = z;
  } else {
    if (blockIdx.x >= 8) return;
    W = W2; Wt = W2t; K = 1024; Nn = 512; e = z - 8;
  }
  size_t eo = (size_t)e * K * Nn;
  int kb = blockIdx.y * 64, nb = blockIdx.x * 64;
  int r = threadIdx.x >> 2, c0 = (threadIdx.x & 3) * 16;
  const float* wp = &W[eo + (size_t)(kb + r) * Nn + nb + c0];
#pragma unroll
  for (int c = 0; c < 16; c += 4) {
    float4 t = *(const float4*)&wp[c];
    T[r][c0 + c + 0] = f2bf(t.x);
    T[r][c0 + c + 1] = f2bf(t.y);
    T[r][c0 + c + 2] = f2bf(t.z);
    T[r][c0 + c + 3] = f2bf(t.w);
  }
  __syncthreads();
  short8 s0, s1;
#pragma unroll
  for (int j = 0; j < 8; ++j) {
    s0[j] = (short)T[c0 + j][r];
    s1[j] = (short)T[c0 + 8 + j][r];
  }
  *(short8*)&Wt[eo + (size_t)(nb + r) * K + kb + c0] = s0;
  *(short8*)&Wt[eo + (size_t)(nb + r) * K + kb + c0 + 8] = s1;
}

// ---------------------------------------------------------------------------
// Fused QKV split-bf16 MFMA GEMM + RoPE. M=4096, N=1536, K=512.
// Flat XCD-pinned grid (384 = 8 xcd x 4 m x 12 n).
// ---------------------------------------------------------------------------
__global__ __launch_bounds__(256) void qkv_mfma(const u16* __restrict__ Ah_g,
                                                const u16* __restrict__ Al_g,
                                                const u16* __restrict__ Bh_g,
                                                const u16* __restrict__ Bl_g,
                                                const float* __restrict__ bq,
                                                const float* __restrict__ bk,
                                                const float* __restrict__ bv,
                                                const float* __restrict__ cosb,
                                                const float* __restrict__ sinb,
                                                u16* __restrict__ qh, u16* __restrict__ ql,
                                                u16* __restrict__ kh, u16* __restrict__ kl,
                                                u16* __restrict__ vb) {
  __shared__ u16 Ah[128][40], Al[128][40], Bh[128][40], Bl[128][40];
  int tid = threadIdx.x;
  int w = tid >> 6, l = tid & 63;
  int wr = w >> 1, wc = w & 1;
  int lg = l >> 4, lx = l & 15;
  int f = blockIdx.x;
  int xcd = f & 7, rr = f >> 3;        // rr 0..47
  int mt = xcd * 4 + (rr & 3);         // 0..31, m-slab pinned to XCD
  int nt = rr >> 2;                    // 0..11
  int m0 = mt * 128, n0 = nt * 128;
  int sr = tid >> 1, s16 = (tid & 1) * 16;
  const u16* Aph = Ah_g + (size_t)(m0 + sr) * 512;
  const u16* Apl = Al_g + (size_t)(m0 + sr) * 512;
  const u16* Bph = Bh_g + (size_t)(n0 + sr) * 512;
  const u16* Bpl = Bl_g + (size_t)(n0 + sr) * 512;
  f32x4 acc[4][4];
#pragma unroll
  for (int m = 0; m < 4; ++m)
#pragma unroll
    for (int n = 0; n < 4; ++n) acc[m][n] = (f32x4){0.f, 0.f, 0.f, 0.f};
  short8 ah0 = *(const short8*)&Aph[s16];
  short8 ah1 = *(const short8*)&Aph[s16 + 8];
  short8 al0 = *(const short8*)&Apl[s16];
  short8 al1 = *(const short8*)&Apl[s16 + 8];
  short8 bh0 = *(const short8*)&Bph[s16];
  short8 bh1 = *(const short8*)&Bph[s16 + 8];
  short8 bl0 = *(const short8*)&Bpl[s16];
  short8 bl1 = *(const short8*)&Bpl[s16 + 8];
  for (int k0 = 0; k0 < 512; k0 += 32) {
    __syncthreads();
    *(short8*)&Ah[sr][s16] = ah0; *(short8*)&Ah[sr][s16 + 8] = ah1;
    *(short8*)&Al[sr][s16] = al0; *(short8*)&Al[sr][s16 + 8] = al1;
    *(short8*)&Bh[sr][s16] = bh0; *(short8*)&Bh[sr][s16 + 8] = bh1;
    *(short8*)&Bl[sr][s16] = bl0; *(short8*)&Bl[sr][s16 + 8] = bl1;
    __syncthreads();
    if (k0 + 32 < 512) {
      int ko = k0 + 32 + s16;
      ah0 = *(const short8*)&Aph[ko]; ah1 = *(const short8*)&Aph[ko + 8];
      al0 = *(const short8*)&Apl[ko]; al1 = *(const short8*)&Apl[ko + 8];
      bh0 = *(const short8*)&Bph[ko]; bh1 = *(const short8*)&Bph[ko + 8];
      bl0 = *(const short8*)&Bpl[ko]; bl1 = *(const short8*)&Bpl[ko + 8];
    }
    short8 fah[4], fal[4], fbh[4], fbl[4];
#pragma unroll
    for (int m = 0; m < 4; ++m) {
      fah[m] = *(const short8*)&Ah[wr * 64 + m * 16 + lx][lg * 8];
      fal[m] = *(const short8*)&Al[wr * 64 + m * 16 + lx][lg * 8];
    }
#pragma unroll
    for (int n = 0; n < 4; ++n) {
      fbh[n] = *(const short8*)&Bh[wc * 64 + n * 16 + lx][lg * 8];
      fbl[n] = *(const short8*)&Bl[wc * 64 + n * 16 + lx][lg * 8];
    }
#pragma unroll
    for (int m = 0; m < 4; ++m)
#pragma unroll
      for (int n = 0; n < 4; ++n) {
        acc[m][n] = __builtin_amdgcn_mfma_f32_16x16x32_bf16(fah[m], fbh[n], acc[m][n], 0, 0, 0);
        acc[m][n] = __builtin_amdgcn_mfma_f32_16x16x32_bf16(fal[m], fbh[n], acc[m][n], 0, 0, 0);
        acc[m][n] = __builtin_amdgcn_mfma_f32_16x16x32_bf16(fah[m], fbl[n], acc[m][n], 0, 0, 0);
      }
  }
  // ---- epilogue ----
  int tcolbase = n0 + wc * 64;
  int tsel = tcolbase >> 9;             // 0=q, 1=k, 2=v
  int hbase = tcolbase & 511;
  const float* bias = (tsel == 0) ? bq : (tsel == 1) ? bk : bv;
  if (tsel == 2) {
#pragma unroll
    for (int m = 0; m < 4; ++m)
#pragma unroll
      for (int i = 0; i < 4; ++i) {
        int row = m0 + wr * 64 + m * 16 + lg * 4 + i;
#pragma unroll
        for (int n = 0; n < 4; ++n) {
          int col = hbase + n * 16 + lx;
          vb[(size_t)row * 512 + col] = f2bf(acc[m][n][i] + bias[col]);
        }
      }
  } else {
    u16* oh = tsel ? kh : qh;
    u16* ol = tsel ? kl : ql;
    float qsc = tsel ? 1.f : 0.125f;
#pragma unroll
    for (int m = 0; m < 4; ++m)
#pragma unroll
      for (int i = 0; i < 4; ++i) {
        int row = m0 + wr * 64 + m * 16 + lg * 4 + i;
        int s = row >> 1;
#pragma unroll
        for (int n = 0; n < 2; ++n) {
          int dln = n * 16 + lx;
          float c  = cosb[s * 64 + dln];
          float sn = sinb[s * 64 + dln];
          float a  = acc[m][n][i]     + bias[hbase + dln];
          float b2 = acc[m][n + 2][i] + bias[hbase + dln + 32];
          float ra = (a * c - b2 * sn) * qsc;
          float rb = (b2 * c + a * sn) * qsc;
          size_t ix = (size_t)row * 512 + hbase + dln;
          u16 rah = f2bf(ra);
          oh[ix] = rah; ol[ix] = f2bf(ra - bf2f(rah));
          u16 rbh = f2bf(rb);
          oh[ix + 32] = rbh; ol[ix + 32] = f2bf(rb - bf2f(rbh));
        }
      }
  }
}

// ---------------------------------------------------------------------------
// MFMA flash attention, KV-split=2, XCD-pinned (b,h,kvh) slabs, QT=128.
// KT=128: one softmax pass per 128 kv rows; PV in two 64-kv sub-chunks.
// ---------------------------------------------------------------------------
__global__ __launch_bounds__(512, 4) void attn_mfma2(const u16* __restrict__ qh,
                                                     const u16* __restrict__ ql,
                                                     const u16* __restrict__ kh,
                                                     const u16* __restrict__ kl,
                                                     const u16* __restrict__ vbuf,
                                                     u16* __restrict__ poh,
                                                     u16* __restrict__ pol,
                                                     float* __restrict__ pml) {
  __shared__ u16 Khi[128][72];
  __shared__ u16 Klo[128][72];
  __shared__ u16 Vt[64][136];          // [d][kv 0..127]
  __shared__ unsigned P2[8][16][32];   // per-wave P chunk (64 kv)
  int tid = threadIdx.x;
  int w = tid >> 6, l = tid & 63;      // w 0..7
  int lg = l >> 4, lx = l & 15;
  int f = blockIdx.x;                  // 0..511
  int xcd = f & 7, j = f >> 3;         // j 0..63
  int slab = xcd + 8 * (j & 3);        // 0..31 : all qt of a slab share an XCD
  int qt = j >> 2;                     // 0..15 (128-row q tiles)
  int bh = slab >> 1, kvh = slab & 1;
  int b = bh >> 3, h = bh & 7;

  short8 qfh[2], qfl[2];
  {
    int qrow = qt * 128 + w * 16 + lx;
    size_t qo = (size_t)(qrow * 2 + b) * 512 + h * 64 + lg * 8;
    qfh[0] = *(const short8*)&qh[qo];
    qfh[1] = *(const short8*)&qh[qo + 32];
    qfl[0] = *(const short8*)&ql[qo];
    qfl[1] = *(const short8*)&ql[qo + 32];
  }

  f32x4 o_acc[4];
#pragma unroll
  for (int dg = 0; dg < 4; ++dg) o_acc[dg] = (f32x4){0.f, 0.f, 0.f, 0.f};
  float m_run = -1e30f, l_run = 0.f;

  int kvr = tid >> 2, ds4 = (tid & 3) * 16;   // K: 128 rows x 64, 16 el/thread
  int kvc = tid & 127, dsg = (tid >> 7) * 16; // V: transpose, 16 el/thread
  int psw = (lx & 7) << 2;                    // P2 bank swizzle

  short8 rkh0, rkh1, rkl0, rkl1, rv0, rv1;
  {
    int t0 = kvh * 1024;
    size_t ko = (size_t)((t0 + kvr) * 2 + b) * 512 + h * 64 + ds4;
    rkh0 = *(const short8*)&kh[ko]; rkh1 = *(const short8*)&kh[ko + 8];
    rkl0 = *(const short8*)&kl[ko]; rkl1 = *(const short8*)&kl[ko + 8];
    size_t vo = (size_t)((t0 + kvc) * 2 + b) * 512 + h * 64 + dsg;
    rv0 = *(const short8*)&vbuf[vo]; rv1 = *(const short8*)&vbuf[vo + 8];
  }

  for (int it = 0; it < 8; ++it) {
    __syncthreads();
    *(short8*)&Khi[kvr][ds4]     = rkh0;
    *(short8*)&Khi[kvr][ds4 + 8] = rkh1;
    *(short8*)&Klo[kvr][ds4]     = rkl0;
    *(short8*)&Klo[kvr][ds4 + 8] = rkl1;
#pragma unroll
    for (int c = 0; c < 8; ++c) {
      Vt[dsg + c][kvc]     = (u16)rv0[c];
      Vt[dsg + 8 + c][kvc] = (u16)rv1[c];
    }
    __syncthreads();
    if (it + 1 < 8) {
      int t0 = kvh * 1024 + (it + 1) * 128;
      size_t ko = (size_t)((t0 + kvr) * 2 + b) * 512 + h * 64 + ds4;
      rkh0 = *(const short8*)&kh[ko]; rkh1 = *(const short8*)&kh[ko + 8];
      rkl0 = *(const short8*)&kl[ko]; rkl1 = *(const short8*)&kl[ko + 8];
      size_t vo = (size_t)((t0 + kvc) * 2 + b) * 512 + h * 64 + dsg;
      rv0 = *(const short8*)&vbuf[vo]; rv1 = *(const short8*)&vbuf[vo + 8];
    }

    // ---- QK^T, swapped: D[kv][q], kv = 16cg+4lg+i (cg 0..7) ----
    f32x4 sc[8];
#pragma unroll
    for (int cg = 0; cg < 8; ++cg) {
      short8 kf0 = *(const short8*)&Khi[cg * 16 + lx][lg * 8];
      short8 kf1 = *(const short8*)&Khi[cg * 16 + lx][32 + lg * 8];
      short8 kg0 = *(const short8*)&Klo[cg * 16 + lx][lg * 8];
      short8 kg1 = *(const short8*)&Klo[cg * 16 + lx][32 + lg * 8];
      f32x4 a = (f32x4){0.f, 0.f, 0.f, 0.f};
      a = __builtin_amdgcn_mfma_f32_16x16x32_bf16(kf0, qfh[0], a, 0, 0, 0);
      a = __builtin_amdgcn_mfma_f32_16x16x32_bf16(kf1, qfh[1], a, 0, 0, 0);
      a = __builtin_amdgcn_mfma_f32_16x16x32_bf16(kf0, qfl[0], a, 0, 0, 0);
      a = __builtin_amdgcn_mfma_f32_16x16x32_bf16(kf1, qfl[1], a, 0, 0, 0);
      a = __builtin_amdgcn_mfma_f32_16x16x32_bf16(kg0, qfh[0], a, 0, 0, 0);
      a = __builtin_amdgcn_mfma_f32_16x16x32_bf16(kg1, qfh[1], a, 0, 0, 0);
      sc[cg] = a;
    }

    // ---- ONE in-register softmax over all 128 kv for q = lx ----
    float tm = sc[0][0];
#pragma unroll
    for (int cg = 0; cg < 8; ++cg)
#pragma unroll
      for (int i = 0; i < 4; ++i) tm = fmaxf(tm, sc[cg][i]);
    tm = fmaxf(tm, __shfl_xor(tm, 16));
    tm = fmaxf(tm, __shfl_xor(tm, 32));
    float mn = fmaxf(m_run, tm);
    float corr = __expf(m_run - mn);
    m_run = mn;
    float ts = 0.f;
#pragma unroll
    for (int cg = 0; cg < 8; ++cg)
#pragma unroll
      for (int i = 0; i < 4; ++i) {
        float pv = __expf(sc[cg][i] - mn);
        sc[cg][i] = pv;
        ts += pv;
      }
    ts += __shfl_xor(ts, 16);
    ts += __shfl_xor(ts, 32);
    l_run = l_run * corr + ts;
#pragma unroll
    for (int dg = 0; dg < 4; ++dg) o_acc[dg] *= corr;

    // ---- PV in two 64-kv chunks, reusing P2 (wave-local) ----
#pragma unroll
    for (int ch = 0; ch < 2; ++ch) {
#pragma unroll
      for (int cg = 0; cg < 4; ++cg)
#pragma unroll
        for (int t = 0; t < 2; ++t) {
          const f32x4& s4 = sc[4 * ch + cg];
          unsigned dw = (unsigned)f2bf(s4[2 * t]) |
                        ((unsigned)f2bf(s4[2 * t + 1]) << 16);
          P2[w][lx][(8 * cg + 2 * lg + t) ^ psw] = dw;
        }
      short8 pf0 = *(const short8*)&P2[w][lx][(4 * lg) ^ psw];
      short8 pf1 = *(const short8*)&P2[w][lx][(16 + 4 * lg) ^ psw];
#pragma unroll
      for (int dg = 0; dg < 4; ++dg) {
        short8 v0 = *(const short8*)&Vt[dg * 16 + lx][ch * 64 + lg * 8];
        short8 v1 = *(const short8*)&Vt[dg * 16 + lx][ch * 64 + 32 + lg * 8];
        o_acc[dg] = __builtin_amdgcn_mfma_f32_16x16x32_bf16(v0, pf0, o_acc[dg], 0, 0, 0);
        o_acc[dg] = __builtin_amdgcn_mfma_f32_16x16x32_bf16(v1, pf1, o_acc[dg], 0, 0, 0);
      }
    }
  }

  // ---- epilogue: lane holds ctx^T[d=16dg+4lg+i][q=lx] ----
  {
    int qrow = qt * 128 + w * 16 + lx;
    int row2 = qrow * 2 + b;
    size_t base = (size_t)kvh * ((size_t)N_ * D_) + (size_t)row2 * 512 + h * 64;
#pragma unroll
    for (int dg = 0; dg < 4; ++dg)
#pragma unroll
      for (int i = 0; i < 4; ++i) {
        int d = dg * 16 + 4 * lg + i;
        float val = o_acc[dg][i];
        u16 hi = f2bf(val);
        poh[base + d] = hi;
        pol[base + d] = f2bf(val - bf2f(hi));
      }
    if (lg == 0) {
      int u = row2 * 8 + h;
      pml[(size_t)kvh * 65536 + u * 2 + 0] = m_run;
      pml[(size_t)kvh * 65536 + u * 2 + 1] = l_run;
    }
  }
}

// Merge the two KV halves -> split-bf16 ctx.
__global__ __launch_bounds__(256) void merge_attn2(const u16* __restrict__ poh,
                                                   const u16* __restrict__ pol,
                                                   const float* __restrict__ pml,
                                                   u16* __restrict__ ch,
                                                   u16* __restrict__ cl) {
  int u = blockIdx.x * 4 + (threadIdx.x >> 6);
  int lane = threadIdx.x & 63;
  float m0 = pml[u * 2], l0 = pml[u * 2 + 1];
  float m1 = pml[65536 + u * 2], l1 = pml[65536 + u * 2 + 1];
  float m = fmaxf(m0, m1);
  float e0 = __expf(m0 - m), e1 = __expf(m1 - m);
  float inv = 1.f / (l0 * e0 + l1 * e1);
  int n = u >> 3, h = u & 7;
  size_t base = (size_t)n * 512 + h * 64 + lane;
  const size_t PO1 = (size_t)N_ * D_;
  float v0 = bf2f(poh[base]) + bf2f(pol[base]);
  float v1 = bf2f(poh[PO1 + base]) + bf2f(pol[PO1 + base]);
  float val = (v0 * e0 + v1 * e1) * inv;
  u16 hi = f2bf(val);
  ch[base] = hi;
  cl[base] = f2bf(val - bf2f(hi));
}

// ---------------------------------------------------------------------------
// Wo projection: split-bf16 MFMA GEMM, M=4096, N=512, K=512, f32 out.
// Flat XCD-pinned grid (128 = 8 xcd x 4 m x 4 n).
// ---------------------------------------------------------------------------
__global__ __launch_bounds__(256) void wo_mfma(const u16* __restrict__ Ah_g,
                                               const u16* __restrict__ Al_g,
                                               const u16* __restrict__ Bh_g,
                                               const u16* __restrict__ Bl_g,
                                               const float* __restrict__ bias,
                                               float* __restrict__ C) {
  __shared__ u16 Ah[128][40], Al[128][40], Bh[128][40], Bl[128][40];
  int tid = threadIdx.x;
  int w = tid >> 6, l = tid & 63;
  int wr = w >> 1, wc = w & 1;
  int lg = l >> 4, lx = l & 15;
  int f = blockIdx.x;
  int xcd = f & 7, rr = f >> 3;        // rr 0..15
  int m0 = (xcd * 4 + (rr & 3)) * 128;
  int n0 = (rr >> 2) * 128;
  int sr = tid >> 1, s16 = (tid & 1) * 16;
  const u16* Aph = Ah_g + (size_t)(m0 + sr) * 512;
  const u16* Apl = Al_g + (size_t)(m0 + sr) * 512;
  const u16* Bph = Bh_g + (size_t)(n0 + sr) * 512;
  const u16* Bpl = Bl_g + (size_t)(n0 + sr) * 512;
  f32x4 acc[4][4];
#pragma unroll
  for (int m = 0; m < 4; ++m)
#pragma unroll
    for (int n = 0; n < 4; ++n) acc[m][n] = (f32x4){0.f, 0.f, 0.f, 0.f};
  short8 ah0 = *(const short8*)&Aph[s16];
  short8 ah1 = *(const short8*)&Aph[s16 + 8];
  short8 al0 = *(const short8*)&Apl[s16];
  short8 al1 = *(const short8*)&Apl[s16 + 8];
  short8 bh0 = *(const short8*)&Bph[s16];
  short8 bh1 = *(const short8*)&Bph[s16 + 8];
  short8 bl0 = *(const short8*)&Bpl[s16];
  short8 bl1 = *(const short8*)&Bpl[s16 + 8];
  for (int k0 = 0; k0 < 512; k0 += 32) {
    __syncthreads();
    *(short8*)&Ah[sr][s16] = ah0; *(short8*)&Ah[sr][s16 + 8] = ah1;
    *(short8*)&Al[sr][s16] = al0; *(short8*)&Al[sr][s16 + 8] = al1;
    *(short8*)&Bh[sr][s16] = bh0; *(short8*)&Bh[sr][s16 + 8] = bh1;
    *(short8*)&Bl[sr][s16] = bl0; *(short8*)&Bl[sr][s16 + 8] = bl1;
    __syncthreads();
    if (k0 + 32 < 512) {
      int ko = k0 + 32 + s16;
      ah0 = *(const short8*)&Aph[ko]; ah1 = *(const short8*)&Aph[ko + 8];
      al0 = *(const short8*)&Apl[ko]; al1 = *(const short8*)&Apl[ko + 8];
      bh0 = *(const short8*)&Bph[ko]; bh1 = *(const short8*)&Bph[ko + 8];
      bl0 = *(const short8*)&Bpl[ko]; bl1 = *(const short8*)&Bpl[ko + 8];
    }
    short8 fah[4], fal[4], fbh[4], fbl[4];
#pragma unroll
    for (int m = 0; m < 4; ++m) {
      fah[m] = *(const short8*)&Ah[wr * 64 + m * 16 + lx][lg * 8];
      fal[m] = *(const short8*)&Al[wr * 64 + m * 16 + lx][lg * 8];
    }
#pragma unroll
    for (int n = 0; n < 4; ++n) {
      fbh[n] = *(const short8*)&Bh[wc * 64 + n * 16 + lx][lg * 8];
      fbl[n] = *(const short8*)&Bl[wc * 64 + n * 16 + lx][lg * 8];
    }
#pragma unroll
    for (int m = 0; m < 4; ++m)
#pragma unroll
      for (int n = 0; n < 4; ++n) {
        acc[m][n] = __builtin_amdgcn_mfma_f32_16x16x32_bf16(fah[m], fbh[n], acc[m][n], 0, 0, 0);
        acc[m][n] = __builtin_amdgcn_mfma_f32_16x16x32_bf16(fal[m], fbh[n], acc[m][n], 0, 0, 0);
        acc[m][n] = __builtin_amdgcn_mfma_f32_16x16x32_bf16(fah[m], fbl[n], acc[m][n], 0, 0, 0);
      }
  }
#pragma unroll
  for (int m = 0; m < 4; ++m)
#pragma unroll
    for (int i = 0; i < 4; ++i) {
      int row = m0 + wr * 64 + m * 16 + lg * 4 + i;
#pragma unroll
      for (int n = 0; n < 4; ++n) {
        int col = n0 + wc * 64 + n * 16 + lx;
        C[(size_t)row * 512 + col] = acc[m][n][i] + bias[col];
      }
    }
}

// ---------------------------------------------------------------------------
// LayerNorm with residual + bf16 copy + FUSED gate top-2.
// ---------------------------------------------------------------------------
__global__ __launch_bounds__(256) void ln_res_gate(const float* __restrict__ a,
                                                   const float* __restrict__ b,
                                                   const float* __restrict__ g,
                                                   const float* __restrict__ beta,
                                                   const float* __restrict__ Wg,
                                                   float* __restrict__ out,
                                                   u16* __restrict__ obf,
                                                   float* __restrict__ gp,
                                                   int* __restrict__ tope) {
  int n = blockIdx.x * 4 + (threadIdx.x >> 6);
  int lane = threadIdx.x & 63;
  float v[8];
  float s = 0.f;
#pragma unroll
  for (int i = 0; i < 8; ++i) {
    int d = lane + 64 * i;
    v[i] = a[(size_t)n * D_ + d] + b[(size_t)n * D_ + d];
    s += v[i];
  }
#pragma unroll
  for (int m = 32; m; m >>= 1) s += __shfl_xor(s, m);
  float mean = s * (1.f / D_);
  float s2 = 0.f;
#pragma unroll
  for (int i = 0; i < 8; ++i) { float t = v[i] - mean; s2 += t * t; }
#pragma unroll
  for (int m = 32; m; m >>= 1) s2 += __shfl_xor(s2, m);
  float r = rsqrtf(s2 * (1.f / D_) + 1e-5f);
  float p[E_] = {};
#pragma unroll
  for (int i = 0; i < 8; ++i) {
    int d = lane + 64 * i;
    float val = (v[i] - mean) * r * g[d] + beta[d];
    out[(size_t)n * D_ + d] = val;
    obf[(size_t)n * D_ + d] = f2bf(val);
    const float* wr = &Wg[(size_t)d * E_];
#pragma unroll
    for (int e = 0; e < E_; ++e) p[e] += val * wr[e];
  }
#pragma unroll
  for (int e = 0; e < E_; ++e)
#pragma unroll
    for (int m = 32; m; m >>= 1) p[e] += __shfl_xor(p[e], m);
  if (lane == 0) {
    float mx = p[0];
#pragma unroll
    for (int e = 1; e < E_; ++e) mx = fmaxf(mx, p[e]);
    float q[E_];
#pragma unroll
    for (int e = 0; e < E_; ++e) q[e] = expf(p[e] - mx);
    int e1 = 0;
#pragma unroll
    for (int e = 1; e < E_; ++e) if (q[e] > q[e1]) e1 = e;
    int e2 = (e1 == 0) ? 1 : 0;
#pragma unroll
    for (int e = 0; e < E_; ++e) if (e != e1 && q[e] > q[e2]) e2 = e;
    float denom = q[e1] + q[e2];
    gp[n * 2] = q[e1] / denom;
    gp[n * 2 + 1] = q[e2] / denom;
    tope[n] = e1 | (e2 << 8);
  }
}

__global__ __launch_bounds__(256) void ln2_final(const float* __restrict__ x,
                                                 const u16* __restrict__ mp,
                                                 const float* __restrict__ g,
                                                 const float* __restrict__ beta,
                                                 float* __restrict__ out) {
  int n = blockIdx.x * 4 + (threadIdx.x >> 6);
  int lane = threadIdx.x & 63;
  float v[8];
  float s = 0.f;
#pragma unroll
  for (int i = 0; i < 8; ++i) {
    int d = lane + 64 * i;
    v[i] = x[(size_t)n * D_ + d] + bf2f(mp[(size_t)(2 * n) * D_ + d]) +
           bf2f(mp[(size_t)(2 * n + 1) * D_ + d]);
    s += v[i];
  }
#pragma unroll
  for (int m = 32; m; m >>= 1) s += __shfl_xor(s, m);
  float mean = s * (1.f / D_);
  float s2 = 0.f;
#pragma unroll
  for (int i = 0; i < 8; ++i) { float t = v[i] - mean; s2 += t * t; }
#pragma unroll
  for (int m = 32; m; m >>= 1) s2 += __shfl_xor(s2, m);
  float r = rsqrtf(s2 * (1.f / D_) + 1e-5f);
#pragma unroll
  for (int i = 0; i < 8; ++i) {
    int d = lane + 64 * i;
    out[(size_t)n * D_ + d] = (v[i] - mean) * r * g[d] + beta[d];
  }
}

// ---------------------------------------------------------------------------
// bf16 MFMA MoE GEMM, 64x128 tile, BK=32, 4 waves (each 64x32 out).
// Flat grid, expert = blockIdx & 7 -> expert pinned to one XCD.
// ---------------------------------------------------------------------------
template <int MODE>
__global__ __launch_bounds__(256) void moe_mfma(const u16* __restrict__ Abase,
                                                const u16* __restrict__ Wt,
                                                const float* __restrict__ bias,
                                                const float* __restrict__ gp,
                                                u16* __restrict__ outp,
                                                const int* __restrict__ cnt,
                                                const int* __restrict__ lst) {
  constexpr int K  = MODE ? 1024 : 512;
  constexpr int Nn = MODE ? 512 : 1024;
  constexpr int NT = Nn / 128;
  constexpr int NI = K / 32;
  int fidx = blockIdx.x;
  int e = fidx & 7;
  int r = fidx >> 3;
  int nt = r % NT;
  int mt = r / NT;
  int c = cnt[e];
  int m0 = mt * 64;
  if (m0 >= c) return;
  int off = 0;
#pragma unroll
  for (int i = 0; i < E_; ++i) if (i < e) off += cnt[i];
  int n0 = nt * 128;
  __shared__ u16 As[64][40];
  __shared__ u16 Bs[128][40];
  int tid = threadIdx.x;
  int w = tid >> 6, l = tid & 63;
  int lg = l >> 4, lx = l & 15;
  int arow = tid >> 2, aseg = (tid & 3) * 8;
  int brow = tid >> 1, bseg = (tid & 1) * 16;
  int ar = m0 + arow; if (ar >= c) ar = c - 1;
  const u16* Ap;
  if (MODE == 0) Ap = Abase + (size_t)(lst[e * N_ + ar] >> 1) * 512 + aseg;
  else           Ap = Abase + (size_t)(off + ar) * 1024 + aseg;
  const u16* Bp = Wt + (size_t)e * K * Nn + (size_t)(n0 + brow) * K + bseg;

  f32x4 acc[4][2];
#pragma unroll
  for (int m = 0; m < 4; ++m)
#pragma unroll
    for (int n = 0; n < 2; ++n) acc[m][n] = (f32x4){0.f, 0.f, 0.f, 0.f};

  short8 pa  = *(const short8*)&Ap[0];
  short8 pb0 = *(const short8*)&Bp[0];
  short8 pb1 = *(const short8*)&Bp[8];
  for (int kk = 0; kk < NI; ++kk) {
    __syncthreads();
    *(short8*)&As[arow][aseg] = pa;
    *(short8*)&Bs[brow][bseg] = pb0;
    *(short8*)&Bs[brow][bseg + 8] = pb1;
    __syncthreads();
    if (kk + 1 < NI) {
      int ko = (kk + 1) * 32;
      pa  = *(const short8*)&Ap[ko];
      pb0 = *(const short8*)&Bp[ko];
      pb1 = *(const short8*)&Bp[ko + 8];
    }
    short8 af[4], bf[2];
#pragma unroll
    for (int m = 0; m < 4; ++m)
      af[m] = *(const short8*)&As[m * 16 + lx][lg * 8];
#pragma unroll
    for (int n = 0; n < 2; ++n)
      bf[n] = *(const short8*)&Bs[w * 32 + n * 16 + lx][lg * 8];
#pragma unroll
    for (int m = 0; m < 4; ++m)
#pragma unroll
      for (int n = 0; n < 2; ++n)
        acc[m][n] = __builtin_amdgcn_mfma_f32_16x16x32_bf16(af[m], bf[n], acc[m][n], 0, 0, 0);
  }
#pragma unroll
  for (int m = 0; m < 4; ++m)
#pragma unroll
    for (int i = 0; i < 4; ++i) {
      int rr = m0 + m * 16 + lg * 4 + i;
      if (rr < c) {
#pragma unroll
        for (int n = 0; n < 2; ++n) {
          int col = n0 + w * 32 + n * 16 + lx;
          float val = acc[m][n][i] + bias[e * Nn + col];
          if (MODE == 0) {
            outp[(size_t)(off + rr) * 1024 + col] = f2bf(fmaxf(val, 0.f));
          } else {
            int p = lst[e * N_ + rr];
            outp[(size_t)p * 512 + col] = f2bf(gp[p] * val);
          }
        }
      }
    }
}

// ---------------------------------------------------------------------------
extern "C" void kernel_launch(void* const* d_in, const int* in_sizes, int n_in,
                              void* d_out, int out_size, void* d_ws, size_t ws_size,
                              hipStream_t stream) {
  const float* src  = (const float*)d_in[0];
  const float* cosb = (const float*)d_in[1];
  const float* sinb = (const float*)d_in[2];
  const float* Wq   = (const float*)d_in[3];
  const float* bq   = (const float*)d_in[4];
  const float* Wk   = (const float*)d_in[5];
  const float* bk   = (const float*)d_in[6];
  const float* Wv   = (const float*)d_in[7];
  const float* bv   = (const float*)d_in[8];
  const float* Wo   = (const float*)d_in[9];
  const float* bo   = (const float*)d_in[10];
  const float* ln1g = (const float*)d_in[11];
  const float* ln1b = (const float*)d_in[12];
  const float* ln2g = (const float*)d_in[13];
  const float* ln2b = (const float*)d_in[14];
  const float* Wg   = (const float*)d_in[15];
  const float* W1   = (const float*)d_in[16];
  const float* B1   = (const float*)d_in[17];
  const float* W2   = (const float*)d_in[18];
  const float* B2   = (const float*)d_in[19];
  float* out = (float*)d_out;
  char* wsb = (char*)d_ws;

  const size_t MB1 = 1u << 20;
  u16* sh   = (u16*)(wsb + 0 * MB1);      // src hi  [0,4M)   ; later ch, then mp
  u16* sl   = (u16*)(wsb + 4 * MB1);      // src lo  [4,8M)   ; later cl
  u16* qhb  = (u16*)(wsb + 8 * MB1);      // [8,12M)          ; later hbf part
  u16* qlb  = (u16*)(wsb + 12 * MB1);
  u16* khb  = (u16*)(wsb + 16 * MB1);
  u16* klb  = (u16*)(wsb + 20 * MB1);
  u16* vbuf = (u16*)(wsb + 24 * MB1);     // [24,28M)
  u16* poh  = (u16*)(wsb + 28 * MB1);     // [28,36M) attn partial hi ; later aob f32, then W2t
  u16* pol  = (u16*)(wsb + 36 * MB1);     // [36,44M) attn partial lo ; later xb f32
  float* pml = (float*)(wsb + 44 * MB1);  // [44,44.5M)       ; later xbf
  float* aob = (float*)(wsb + 28 * MB1);  // [28,36M)
  float* xb  = (float*)(wsb + 36 * MB1);  // [36,44M)
  u16* xbf   = (u16*)(wsb + 44 * MB1);    // [44,48M)
  u16* Wqkv_hi = (u16*)(wsb + 48 * MB1);              // 1.5MB
  u16* Wqkv_lo = (u16*)(wsb + 48 * MB1 + 1572864);    // 1.5MB
  u16* Wo_hi   = (u16*)(wsb + 48 * MB1 + 3145728);    // 0.5MB
  u16* Wo_lo   = (u16*)(wsb + 48 * MB1 + 3670016);    // 0.5MB
  u16* W1t     = (u16*)(wsb + 52 * MB1);  // [52,60M)
  u16* W2t     = (u16*)(wsb + 28 * MB1);  // [28,36M) — written after ln_res_gate (aob dead)
  float* gpb   = (float*)(wsb + 60 * MB1);                 // 32 KB
  int* cnt     = (int*)(wsb + 60 * MB1 + 32768);           // 64 B
  int* lst     = (int*)(wsb + 60 * MB1 + 32768 + 64);      // 128 KB
  int* tope    = (int*)(wsb + 60 * MB1 + 32768 + 64 + 131072);  // 16 KB
  u16* ch  = sh;                          // ctx hi aliases src-split (dead)
  u16* cl  = sl;
  u16* hbf = (u16*)(wsb + 8 * MB1);       // [8,24M) aliases q/k (dead after attn)
  u16* mp  = (u16*)(wsb + 0 * MB1);       // [0,8M)  aliases ch/cl (dead after wo)

  dim3 blk(256);
  // Weight splits + src split in ONE launch
  wsplit_all<<<dim3(8, 8, 20), blk, 0, stream>>>(Wq, Wk, Wv, Wo, src,
                                                 Wqkv_hi, Wqkv_lo, Wo_hi, Wo_lo,
                                                 sh, sl);
  // QKV + RoPE fused (split-bf16, f32-grade), XCD-pinned flat grid
  qkv_mfma<<<dim3(384), blk, 0, stream>>>(sh, sl, Wqkv_hi, Wqkv_lo, bq, bk, bv,
                                          cosb, sinb, qhb, qlb, khb, klb, vbuf);
  // Attention, KV-split=2, XCD-pinned slabs, QT=128, KT=128
  attn_mfma2<<<dim3(512), dim3(512), 0, stream>>>(qhb, qlb, khb, klb, vbuf, poh, pol, pml);
  merge_attn2<<<dim3(8192), blk, 0, stream>>>(poh, pol, pml, ch, cl);
  // Wo projection (split-bf16), XCD-pinned flat grid
  wo_mfma<<<dim3(128), blk, 0, stream>>>(ch, cl, Wo_hi, Wo_lo, bo, aob);
  // LN1 + fused gate top-2
  ln_res_gate<<<dim3(1024), blk, 0, stream>>>(src, aob, ln1g, ln1b, Wg, xb, xbf, gpb, tope);
  // MoE weight transposes + ordered routing in ONE launch
  wtrans_all<<<dim3(16, 16, 17), blk, 0, stream>>>(W1, W2, W1t, W2t, tope, cnt, lst);
  // Sparse MoE expert GEMMs — 64x128 tiles, expert pinned to XCD
  moe_mfma<0><<<dim3(8 * 8 * 64), blk, 0, stream>>>(xbf, W1t, B1, gpb, hbf, cnt, lst);
  moe_mfma<1><<<dim3(8 * 4 * 64), blk, 0, stream>>>(hbf, W2t, B2, gpb, mp, cnt, lst);
  ln2_final<<<dim3(1024), blk, 0, stream>>>(xb, mp, ln2g, ln2b, out);
}

// Round 19
// 204.987 us; speedup vs baseline: 1.0667x; 1.0190x over previous
//
#include <hip/hip_runtime.h>
#include <math.h>

// Shapes (fixed)
#define S_  2048
#define B_  2
#define D_  512
#define H_  8
#define DH_ 64
#define E_  8
#define F_  1024
#define N_  4096   // S_*B_
#define NPAIR_ 8192

typedef __attribute__((ext_vector_type(4))) float f32x4;
typedef __attribute__((ext_vector_type(8))) short short8;
typedef unsigned short u16;

__device__ __forceinline__ u16 f2bf(float f) {
  unsigned u = __builtin_bit_cast(unsigned, f);
  u += 0x7fffu + ((u >> 16) & 1u);
  return (u16)(u >> 16);
}
__device__ __forceinline__ float bf2f(u16 h) {
  unsigned u = ((unsigned)h) << 16;
  return __builtin_bit_cast(float, u);
}

// ---------------------------------------------------------------------------
// Weight transpose + split (device body): Whi/Wlo[n][k] = split(W[k][n]).
// ---------------------------------------------------------------------------
__device__ __forceinline__ void wsplit_body(const float* __restrict__ W,
                                            u16* __restrict__ Whi,
                                            u16* __restrict__ Wlo,
                                            int Nn, int K, int kb, int nb) {
  __shared__ u16 Th[64][72];
  __shared__ u16 Tl[64][72];
  int r = threadIdx.x >> 2, c0 = (threadIdx.x & 3) * 16;
  const float* wp = &W[(size_t)(kb + r) * Nn + nb + c0];
#pragma unroll
  for (int c = 0; c < 16; c += 4) {
    float4 t = *(const float4*)&wp[c];
    float f[4] = {t.x, t.y, t.z, t.w};
#pragma unroll
    for (int j = 0; j < 4; ++j) {
      u16 a = f2bf(f[j]);
      Th[r][c0 + c + j] = a;
      Tl[r][c0 + c + j] = f2bf(f[j] - bf2f(a));
    }
  }
  __syncthreads();
  short8 h0, h1, l0, l1;
#pragma unroll
  for (int j = 0; j < 8; ++j) {
    h0[j] = (short)Th[c0 + j][r];     h1[j] = (short)Th[c0 + 8 + j][r];
    l0[j] = (short)Tl[c0 + j][r];     l1[j] = (short)Tl[c0 + 8 + j][r];
  }
  size_t ob = (size_t)(nb + r) * K + kb + c0;
  *(short8*)&Whi[ob] = h0;  *(short8*)&Whi[ob + 8] = h1;
  *(short8*)&Wlo[ob] = l0;  *(short8*)&Wlo[ob + 8] = l1;
}

// One launch: Wq/Wk/Wv/Wo splits (z<4) + src split (z>=4). grid (8,8,20).
__global__ __launch_bounds__(256) void wsplit_all(const float* __restrict__ Wq,
                                                  const float* __restrict__ Wk,
                                                  const float* __restrict__ Wv,
                                                  const float* __restrict__ Wo,
                                                  const float* __restrict__ src,
                                                  u16* __restrict__ Wqkv_hi,
                                                  u16* __restrict__ Wqkv_lo,
                                                  u16* __restrict__ Wo_hi,
                                                  u16* __restrict__ Wo_lo,
                                                  u16* __restrict__ sh,
                                                  u16* __restrict__ sl) {
  int z = blockIdx.z;
  if (z < 4) {
    const float* W = (z == 0) ? Wq : (z == 1) ? Wk : (z == 2) ? Wv : Wo;
    u16* Whi = (z == 3) ? Wo_hi : Wqkv_hi + (size_t)z * 512 * 512;
    u16* Wlo = (z == 3) ? Wo_lo : Wqkv_lo + (size_t)z * 512 * 512;
    wsplit_body(W, Whi, Wlo, 512, 512, blockIdx.y * 64, blockIdx.x * 64);
  } else {
    int idx = (z - 4) * 64 + blockIdx.y * 8 + blockIdx.x;
    size_t i = ((size_t)idx * 256 + threadIdx.x) * 8;
    float f[8];
    *(float4*)&f[0] = *(const float4*)&src[i];
    *(float4*)&f[4] = *(const float4*)&src[i + 4];
    short8 h, l;
#pragma unroll
    for (int j = 0; j < 8; ++j) {
      u16 a = f2bf(f[j]);
      h[j] = (short)a;
      l[j] = (short)f2bf(f[j] - bf2f(a));
    }
    *(short8*)&sh[i] = h;
    *(short8*)&sl[i] = l;
  }
}

// ---------------------------------------------------------------------------
// MoE weight transpose (W1+W2) + route_build in ONE launch.
// grid (16,16,17): z<8 W1 expert z; z<16 W2 expert z-8; z==16 route (8 blocks).
// ---------------------------------------------------------------------------
__global__ __launch_bounds__(256) void wtrans_all(const float* __restrict__ W1,
                                                  const float* __restrict__ W2,
                                                  u16* __restrict__ W1t,
                                                  u16* __restrict__ W2t,
                                                  const int* __restrict__ tope,
                                                  int* __restrict__ cnt,
                                                  int* __restrict__ lst) {
  int z = blockIdx.z;
  __shared__ u16 T[64][72];
  __shared__ int wsum[4];
  __shared__ int basem;
  if (z == 16) {
    if (blockIdx.x >= 8 || blockIdx.y != 0) return;
    int e = blockIdx.x;
    int tid = threadIdx.x;
    int w = tid >> 6, lane = tid & 63;
    if (tid == 0) basem = 0;
    __syncthreads();
    for (int c0 = 0; c0 < N_; c0 += 256) {
      int n = c0 + tid;
      int te = tope[n];
      int e1 = te & 0xff, e2 = (te >> 8) & 0xff;
      bool m2 = (e2 == e);
      bool flag = (e1 == e) || m2;
      unsigned long long mask = __ballot(flag);
      int wpre = __popcll(mask & ((1ull << lane) - 1ull));
      if (lane == 0) wsum[w] = __popcll(mask);
      __syncthreads();
      int woff = 0;
      for (int i = 0; i < w; ++i) woff += wsum[i];
      int total = wsum[0] + wsum[1] + wsum[2] + wsum[3];
      if (flag) lst[e * N_ + basem + woff + wpre] = n * 2 + (m2 ? 1 : 0);
      __syncthreads();
      if (tid == 0) basem += total;
      __syncthreads();
    }
    if (tid == 0) cnt[e] = basem;
    return;
  }
  const float* W;
  u16* Wt;
  int K, Nn, e;
  if (z < 8) {
    if (blockIdx.y >= 8) return;
    W = W1; Wt = W1t; K = 512; Nn = 1024; e = z;
  } else {
    if (blockIdx.x >= 8) return;
    W = W2; Wt = W2t; K = 1024; Nn = 512; e = z - 8;
  }
  size_t eo = (size_t)e * K * Nn;
  int kb = blockIdx.y * 64, nb = blockIdx.x * 64;
  int r = threadIdx.x >> 2, c0 = (threadIdx.x & 3) * 16;
  const float* wp = &W[eo + (size_t)(kb + r) * Nn + nb + c0];
#pragma unroll
  for (int c = 0; c < 16; c += 4) {
    float4 t = *(const float4*)&wp[c];
    T[r][c0 + c + 0] = f2bf(t.x);
    T[r][c0 + c + 1] = f2bf(t.y);
    T[r][c0 + c + 2] = f2bf(t.z);
    T[r][c0 + c + 3] = f2bf(t.w);
  }
  __syncthreads();
  short8 s0, s1;
#pragma unroll
  for (int j = 0; j < 8; ++j) {
    s0[j] = (short)T[c0 + j][r];
    s1[j] = (short)T[c0 + 8 + j][r];
  }
  *(short8*)&Wt[eo + (size_t)(nb + r) * K + kb + c0] = s0;
  *(short8*)&Wt[eo + (size_t)(nb + r) * K + kb + c0 + 8] = s1;
}

// ---------------------------------------------------------------------------
// Fused QKV split-bf16 MFMA GEMM + RoPE. M=4096, N=1536, K=512.
// Flat XCD-pinned grid (384 = 8 xcd x 4 m x 12 n).
// V-blocks (nt>=8): B-lo term skipped (output is bf16-quantized anyway).
// ---------------------------------------------------------------------------
__global__ __launch_bounds__(256) void qkv_mfma(const u16* __restrict__ Ah_g,
                                                const u16* __restrict__ Al_g,
                                                const u16* __restrict__ Bh_g,
                                                const u16* __restrict__ Bl_g,
                                                const float* __restrict__ bq,
                                                const float* __restrict__ bk,
                                                const float* __restrict__ bv,
                                                const float* __restrict__ cosb,
                                                const float* __restrict__ sinb,
                                                u16* __restrict__ qh, u16* __restrict__ ql,
                                                u16* __restrict__ kh, u16* __restrict__ kl,
                                                u16* __restrict__ vb) {
  __shared__ u16 Ah[128][40], Al[128][40], Bh[128][40], Bl[128][40];
  int tid = threadIdx.x;
  int w = tid >> 6, l = tid & 63;
  int wr = w >> 1, wc = w & 1;
  int lg = l >> 4, lx = l & 15;
  int f = blockIdx.x;
  int xcd = f & 7, rr = f >> 3;        // rr 0..47
  int mt = xcd * 4 + (rr & 3);         // 0..31, m-slab pinned to XCD
  int nt = rr >> 2;                    // 0..11
  bool qk = (nt < 8);                  // q/k blocks: full 3-product precision
  int m0 = mt * 128, n0 = nt * 128;
  int sr = tid >> 1, s16 = (tid & 1) * 16;
  const u16* Aph = Ah_g + (size_t)(m0 + sr) * 512;
  const u16* Apl = Al_g + (size_t)(m0 + sr) * 512;
  const u16* Bph = Bh_g + (size_t)(n0 + sr) * 512;
  const u16* Bpl = Bl_g + (size_t)(n0 + sr) * 512;
  f32x4 acc[4][4];
#pragma unroll
  for (int m = 0; m < 4; ++m)
#pragma unroll
    for (int n = 0; n < 4; ++n) acc[m][n] = (f32x4){0.f, 0.f, 0.f, 0.f};
  short8 ah0 = *(const short8*)&Aph[s16];
  short8 ah1 = *(const short8*)&Aph[s16 + 8];
  short8 al0 = *(const short8*)&Apl[s16];
  short8 al1 = *(const short8*)&Apl[s16 + 8];
  short8 bh0 = *(const short8*)&Bph[s16];
  short8 bh1 = *(const short8*)&Bph[s16 + 8];
  short8 bl0, bl1;
  if (qk) {
    bl0 = *(const short8*)&Bpl[s16];
    bl1 = *(const short8*)&Bpl[s16 + 8];
  }
  for (int k0 = 0; k0 < 512; k0 += 32) {
    __syncthreads();
    *(short8*)&Ah[sr][s16] = ah0; *(short8*)&Ah[sr][s16 + 8] = ah1;
    *(short8*)&Al[sr][s16] = al0; *(short8*)&Al[sr][s16 + 8] = al1;
    *(short8*)&Bh[sr][s16] = bh0; *(short8*)&Bh[sr][s16 + 8] = bh1;
    if (qk) {
      *(short8*)&Bl[sr][s16] = bl0; *(short8*)&Bl[sr][s16 + 8] = bl1;
    }
    __syncthreads();
    if (k0 + 32 < 512) {
      int ko = k0 + 32 + s16;
      ah0 = *(const short8*)&Aph[ko]; ah1 = *(const short8*)&Aph[ko + 8];
      al0 = *(const short8*)&Apl[ko]; al1 = *(const short8*)&Apl[ko + 8];
      bh0 = *(const short8*)&Bph[ko]; bh1 = *(const short8*)&Bph[ko + 8];
      if (qk) {
        bl0 = *(const short8*)&Bpl[ko]; bl1 = *(const short8*)&Bpl[ko + 8];
      }
    }
    short8 fah[4], fal[4], fbh[4], fbl[4];
#pragma unroll
    for (int m = 0; m < 4; ++m) {
      fah[m] = *(const short8*)&Ah[wr * 64 + m * 16 + lx][lg * 8];
      fal[m] = *(const short8*)&Al[wr * 64 + m * 16 + lx][lg * 8];
    }
#pragma unroll
    for (int n = 0; n < 4; ++n) {
      fbh[n] = *(const short8*)&Bh[wc * 64 + n * 16 + lx][lg * 8];
    }
    if (qk) {
#pragma unroll
      for (int n = 0; n < 4; ++n)
        fbl[n] = *(const short8*)&Bl[wc * 64 + n * 16 + lx][lg * 8];
    }
#pragma unroll
    for (int m = 0; m < 4; ++m)
#pragma unroll
      for (int n = 0; n < 4; ++n) {
        acc[m][n] = __builtin_amdgcn_mfma_f32_16x16x32_bf16(fah[m], fbh[n], acc[m][n], 0, 0, 0);
        acc[m][n] = __builtin_amdgcn_mfma_f32_16x16x32_bf16(fal[m], fbh[n], acc[m][n], 0, 0, 0);
      }
    if (qk) {
#pragma unroll
      for (int m = 0; m < 4; ++m)
#pragma unroll
        for (int n = 0; n < 4; ++n)
          acc[m][n] = __builtin_amdgcn_mfma_f32_16x16x32_bf16(fah[m], fbl[n], acc[m][n], 0, 0, 0);
    }
  }
  // ---- epilogue ----
  int tcolbase = n0 + wc * 64;
  int tsel = tcolbase >> 9;             // 0=q, 1=k, 2=v
  int hbase = tcolbase & 511;
  const float* bias = (tsel == 0) ? bq : (tsel == 1) ? bk : bv;
  if (tsel == 2) {
#pragma unroll
    for (int m = 0; m < 4; ++m)
#pragma unroll
      for (int i = 0; i < 4; ++i) {
        int row = m0 + wr * 64 + m * 16 + lg * 4 + i;
#pragma unroll
        for (int n = 0; n < 4; ++n) {
          int col = hbase + n * 16 + lx;
          vb[(size_t)row * 512 + col] = f2bf(acc[m][n][i] + bias[col]);
        }
      }
  } else {
    u16* oh = tsel ? kh : qh;
    u16* ol = tsel ? kl : ql;
    float qsc = tsel ? 1.f : 0.125f;
#pragma unroll
    for (int m = 0; m < 4; ++m)
#pragma unroll
      for (int i = 0; i < 4; ++i) {
        int row = m0 + wr * 64 + m * 16 + lg * 4 + i;
        int s = row >> 1;
#pragma unroll
        for (int n = 0; n < 2; ++n) {
          int dln = n * 16 + lx;
          float c  = cosb[s * 64 + dln];
          float sn = sinb[s * 64 + dln];
          float a  = acc[m][n][i]     + bias[hbase + dln];
          float b2 = acc[m][n + 2][i] + bias[hbase + dln + 32];
          float ra = (a * c - b2 * sn) * qsc;
          float rb = (b2 * c + a * sn) * qsc;
          size_t ix = (size_t)row * 512 + hbase + dln;
          u16 rah = f2bf(ra);
          oh[ix] = rah; ol[ix] = f2bf(ra - bf2f(rah));
          u16 rbh = f2bf(rb);
          oh[ix + 32] = rbh; ol[ix + 32] = f2bf(rb - bf2f(rbh));
        }
      }
  }
}

// ---------------------------------------------------------------------------
// MFMA flash attention, KV-split=2, XCD-pinned (b,h,kvh) slabs, QT=128.
// KT=128: one softmax pass per 128 kv rows; PV in two 64-kv sub-chunks.
// ---------------------------------------------------------------------------
__global__ __launch_bounds__(512, 4) void attn_mfma2(const u16* __restrict__ qh,
                                                     const u16* __restrict__ ql,
                                                     const u16* __restrict__ kh,
                                                     const u16* __restrict__ kl,
                                                     const u16* __restrict__ vbuf,
                                                     u16* __restrict__ poh,
                                                     u16* __restrict__ pol,
                                                     float* __restrict__ pml) {
  __shared__ u16 Khi[128][72];
  __shared__ u16 Klo[128][72];
  __shared__ u16 Vt[64][136];          // [d][kv 0..127]
  __shared__ unsigned P2[8][16][32];   // per-wave P chunk (64 kv)
  int tid = threadIdx.x;
  int w = tid >> 6, l = tid & 63;      // w 0..7
  int lg = l >> 4, lx = l & 15;
  int f = blockIdx.x;                  // 0..511
  int xcd = f & 7, j = f >> 3;         // j 0..63
  int slab = xcd + 8 * (j & 3);        // 0..31 : all qt of a slab share an XCD
  int qt = j >> 2;                     // 0..15 (128-row q tiles)
  int bh = slab >> 1, kvh = slab & 1;
  int b = bh >> 3, h = bh & 7;

  short8 qfh[2], qfl[2];
  {
    int qrow = qt * 128 + w * 16 + lx;
    size_t qo = (size_t)(qrow * 2 + b) * 512 + h * 64 + lg * 8;
    qfh[0] = *(const short8*)&qh[qo];
    qfh[1] = *(const short8*)&qh[qo + 32];
    qfl[0] = *(const short8*)&ql[qo];
    qfl[1] = *(const short8*)&ql[qo + 32];
  }

  f32x4 o_acc[4];
#pragma unroll
  for (int dg = 0; dg < 4; ++dg) o_acc[dg] = (f32x4){0.f, 0.f, 0.f, 0.f};
  float m_run = -1e30f, l_run = 0.f;

  int kvr = tid >> 2, ds4 = (tid & 3) * 16;   // K: 128 rows x 64, 16 el/thread
  int kvc = tid & 127, dsg = (tid >> 7) * 16; // V: transpose, 16 el/thread
  int psw = (lx & 7) << 2;                    // P2 bank swizzle

  short8 rkh0, rkh1, rkl0, rkl1, rv0, rv1;
  {
    int t0 = kvh * 1024;
    size_t ko = (size_t)((t0 + kvr) * 2 + b) * 512 + h * 64 + ds4;
    rkh0 = *(const short8*)&kh[ko]; rkh1 = *(const short8*)&kh[ko + 8];
    rkl0 = *(const short8*)&kl[ko]; rkl1 = *(const short8*)&kl[ko + 8];
    size_t vo = (size_t)((t0 + kvc) * 2 + b) * 512 + h * 64 + dsg;
    rv0 = *(const short8*)&vbuf[vo]; rv1 = *(const short8*)&vbuf[vo + 8];
  }

  for (int it = 0; it < 8; ++it) {
    __syncthreads();
    *(short8*)&Khi[kvr][ds4]     = rkh0;
    *(short8*)&Khi[kvr][ds4 + 8] = rkh1;
    *(short8*)&Klo[kvr][ds4]     = rkl0;
    *(short8*)&Klo[kvr][ds4 + 8] = rkl1;
#pragma unroll
    for (int c = 0; c < 8; ++c) {
      Vt[dsg + c][kvc]     = (u16)rv0[c];
      Vt[dsg + 8 + c][kvc] = (u16)rv1[c];
    }
    __syncthreads();
    if (it + 1 < 8) {
      int t0 = kvh * 1024 + (it + 1) * 128;
      size_t ko = (size_t)((t0 + kvr) * 2 + b) * 512 + h * 64 + ds4;
      rkh0 = *(const short8*)&kh[ko]; rkh1 = *(const short8*)&kh[ko + 8];
      rkl0 = *(const short8*)&kl[ko]; rkl1 = *(const short8*)&kl[ko + 8];
      size_t vo = (size_t)((t0 + kvc) * 2 + b) * 512 + h * 64 + dsg;
      rv0 = *(const short8*)&vbuf[vo]; rv1 = *(const short8*)&vbuf[vo + 8];
    }

    // ---- QK^T, swapped: D[kv][q], kv = 16cg+4lg+i (cg 0..7) ----
    f32x4 sc[8];
#pragma unroll
    for (int cg = 0; cg < 8; ++cg) {
      short8 kf0 = *(const short8*)&Khi[cg * 16 + lx][lg * 8];
      short8 kf1 = *(const short8*)&Khi[cg * 16 + lx][32 + lg * 8];
      short8 kg0 = *(const short8*)&Klo[cg * 16 + lx][lg * 8];
      short8 kg1 = *(const short8*)&Klo[cg * 16 + lx][32 + lg * 8];
      f32x4 a = (f32x4){0.f, 0.f, 0.f, 0.f};
      a = __builtin_amdgcn_mfma_f32_16x16x32_bf16(kf0, qfh[0], a, 0, 0, 0);
      a = __builtin_amdgcn_mfma_f32_16x16x32_bf16(kf1, qfh[1], a, 0, 0, 0);
      a = __builtin_amdgcn_mfma_f32_16x16x32_bf16(kf0, qfl[0], a, 0, 0, 0);
      a = __builtin_amdgcn_mfma_f32_16x16x32_bf16(kf1, qfl[1], a, 0, 0, 0);
      a = __builtin_amdgcn_mfma_f32_16x16x32_bf16(kg0, qfh[0], a, 0, 0, 0);
      a = __builtin_amdgcn_mfma_f32_16x16x32_bf16(kg1, qfh[1], a, 0, 0, 0);
      sc[cg] = a;
    }

    // ---- ONE in-register softmax over all 128 kv for q = lx ----
    float tm = sc[0][0];
#pragma unroll
    for (int cg = 0; cg < 8; ++cg)
#pragma unroll
      for (int i = 0; i < 4; ++i) tm = fmaxf(tm, sc[cg][i]);
    tm = fmaxf(tm, __shfl_xor(tm, 16));
    tm = fmaxf(tm, __shfl_xor(tm, 32));
    float mn = fmaxf(m_run, tm);
    float corr = __expf(m_run - mn);
    m_run = mn;
    float ts = 0.f;
#pragma unroll
    for (int cg = 0; cg < 8; ++cg)
#pragma unroll
      for (int i = 0; i < 4; ++i) {
        float pv = __expf(sc[cg][i] - mn);
        sc[cg][i] = pv;
        ts += pv;
      }
    ts += __shfl_xor(ts, 16);
    ts += __shfl_xor(ts, 32);
    l_run = l_run * corr + ts;
#pragma unroll
    for (int dg = 0; dg < 4; ++dg) o_acc[dg] *= corr;

    // ---- PV in two 64-kv chunks, reusing P2 (wave-local) ----
#pragma unroll
    for (int ch = 0; ch < 2; ++ch) {
#pragma unroll
      for (int cg = 0; cg < 4; ++cg)
#pragma unroll
        for (int t = 0; t < 2; ++t) {
          const f32x4& s4 = sc[4 * ch + cg];
          unsigned dw = (unsigned)f2bf(s4[2 * t]) |
                        ((unsigned)f2bf(s4[2 * t + 1]) << 16);
          P2[w][lx][(8 * cg + 2 * lg + t) ^ psw] = dw;
        }
      short8 pf0 = *(const short8*)&P2[w][lx][(4 * lg) ^ psw];
      short8 pf1 = *(const short8*)&P2[w][lx][(16 + 4 * lg) ^ psw];
#pragma unroll
      for (int dg = 0; dg < 4; ++dg) {
        short8 v0 = *(const short8*)&Vt[dg * 16 + lx][ch * 64 + lg * 8];
        short8 v1 = *(const short8*)&Vt[dg * 16 + lx][ch * 64 + 32 + lg * 8];
        o_acc[dg] = __builtin_amdgcn_mfma_f32_16x16x32_bf16(v0, pf0, o_acc[dg], 0, 0, 0);
        o_acc[dg] = __builtin_amdgcn_mfma_f32_16x16x32_bf16(v1, pf1, o_acc[dg], 0, 0, 0);
      }
    }
  }

  // ---- epilogue: lane holds ctx^T[d=16dg+4lg+i][q=lx] ----
  {
    int qrow = qt * 128 + w * 16 + lx;
    int row2 = qrow * 2 + b;
    size_t base = (size_t)kvh * ((size_t)N_ * D_) + (size_t)row2 * 512 + h * 64;
#pragma unroll
    for (int dg = 0; dg < 4; ++dg)
#pragma unroll
      for (int i = 0; i < 4; ++i) {
        int d = dg * 16 + 4 * lg + i;
        float val = o_acc[dg][i];
        u16 hi = f2bf(val);
        poh[base + d] = hi;
        pol[base + d] = f2bf(val - bf2f(hi));
      }
    if (lg == 0) {
      int u = row2 * 8 + h;
      pml[(size_t)kvh * 65536 + u * 2 + 0] = m_run;
      pml[(size_t)kvh * 65536 + u * 2 + 1] = l_run;
    }
  }
}

// Merge the two KV halves -> split-bf16 ctx.
__global__ __launch_bounds__(256) void merge_attn2(const u16* __restrict__ poh,
                                                   const u16* __restrict__ pol,
                                                   const float* __restrict__ pml,
                                                   u16* __restrict__ ch,
                                                   u16* __restrict__ cl) {
  int u = blockIdx.x * 4 + (threadIdx.x >> 6);
  int lane = threadIdx.x & 63;
  float m0 = pml[u * 2], l0 = pml[u * 2 + 1];
  float m1 = pml[65536 + u * 2], l1 = pml[65536 + u * 2 + 1];
  float m = fmaxf(m0, m1);
  float e0 = __expf(m0 - m), e1 = __expf(m1 - m);
  float inv = 1.f / (l0 * e0 + l1 * e1);
  int n = u >> 3, h = u & 7;
  size_t base = (size_t)n * 512 + h * 64 + lane;
  const size_t PO1 = (size_t)N_ * D_;
  float v0 = bf2f(poh[base]) + bf2f(pol[base]);
  float v1 = bf2f(poh[PO1 + base]) + bf2f(pol[PO1 + base]);
  float val = (v0 * e0 + v1 * e1) * inv;
  u16 hi = f2bf(val);
  ch[base] = hi;
  cl[base] = f2bf(val - bf2f(hi));
}

// ---------------------------------------------------------------------------
// Wo projection: split-bf16 MFMA GEMM, M=4096, N=512, K=512, f32 out.
// Flat XCD-pinned grid (128 = 8 xcd x 4 m x 4 n).
// ---------------------------------------------------------------------------
__global__ __launch_bounds__(256) void wo_mfma(const u16* __restrict__ Ah_g,
                                               const u16* __restrict__ Al_g,
                                               const u16* __restrict__ Bh_g,
                                               const u16* __restrict__ Bl_g,
                                               const float* __restrict__ bias,
                                               float* __restrict__ C) {
  __shared__ u16 Ah[128][40], Al[128][40], Bh[128][40], Bl[128][40];
  int tid = threadIdx.x;
  int w = tid >> 6, l = tid & 63;
  int wr = w >> 1, wc = w & 1;
  int lg = l >> 4, lx = l & 15;
  int f = blockIdx.x;
  int xcd = f & 7, rr = f >> 3;        // rr 0..15
  int m0 = (xcd * 4 + (rr & 3)) * 128;
  int n0 = (rr >> 2) * 128;
  int sr = tid >> 1, s16 = (tid & 1) * 16;
  const u16* Aph = Ah_g + (size_t)(m0 + sr) * 512;
  const u16* Apl = Al_g + (size_t)(m0 + sr) * 512;
  const u16* Bph = Bh_g + (size_t)(n0 + sr) * 512;
  const u16* Bpl = Bl_g + (size_t)(n0 + sr) * 512;
  f32x4 acc[4][4];
#pragma unroll
  for (int m = 0; m < 4; ++m)
#pragma unroll
    for (int n = 0; n < 4; ++n) acc[m][n] = (f32x4){0.f, 0.f, 0.f, 0.f};
  short8 ah0 = *(const short8*)&Aph[s16];
  short8 ah1 = *(const short8*)&Aph[s16 + 8];
  short8 al0 = *(const short8*)&Apl[s16];
  short8 al1 = *(const short8*)&Apl[s16 + 8];
  short8 bh0 = *(const short8*)&Bph[s16];
  short8 bh1 = *(const short8*)&Bph[s16 + 8];
  short8 bl0 = *(const short8*)&Bpl[s16];
  short8 bl1 = *(const short8*)&Bpl[s16 + 8];
  for (int k0 = 0; k0 < 512; k0 += 32) {
    __syncthreads();
    *(short8*)&Ah[sr][s16] = ah0; *(short8*)&Ah[sr][s16 + 8] = ah1;
    *(short8*)&Al[sr][s16] = al0; *(short8*)&Al[sr][s16 + 8] = al1;
    *(short8*)&Bh[sr][s16] = bh0; *(short8*)&Bh[sr][s16 + 8] = bh1;
    *(short8*)&Bl[sr][s16] = bl0; *(short8*)&Bl[sr][s16 + 8] = bl1;
    __syncthreads();
    if (k0 + 32 < 512) {
      int ko = k0 + 32 + s16;
      ah0 = *(const short8*)&Aph[ko]; ah1 = *(const short8*)&Aph[ko + 8];
      al0 = *(const short8*)&Apl[ko]; al1 = *(const short8*)&Apl[ko + 8];
      bh0 = *(const short8*)&Bph[ko]; bh1 = *(const short8*)&Bph[ko + 8];
      bl0 = *(const short8*)&Bpl[ko]; bl1 = *(const short8*)&Bpl[ko + 8];
    }
    short8 fah[4], fal[4], fbh[4], fbl[4];
#pragma unroll
    for (int m = 0; m < 4; ++m) {
      fah[m] = *(const short8*)&Ah[wr * 64 + m * 16 + lx][lg * 8];
      fal[m] = *(const short8*)&Al[wr * 64 + m * 16 + lx][lg * 8];
    }
#pragma unroll
    for (int n = 0; n < 4; ++n) {
      fbh[n] = *(const short8*)&Bh[wc * 64 + n * 16 + lx][lg * 8];
      fbl[n] = *(const short8*)&Bl[wc * 64 + n * 16 + lx][lg * 8];
    }
#pragma unroll
    for (int m = 0; m < 4; ++m)
#pragma unroll
      for (int n = 0; n < 4; ++n) {
        acc[m][n] = __builtin_amdgcn_mfma_f32_16x16x32_bf16(fah[m], fbh[n], acc[m][n], 0, 0, 0);
        acc[m][n] = __builtin_amdgcn_mfma_f32_16x16x32_bf16(fal[m], fbh[n], acc[m][n], 0, 0, 0);
        acc[m][n] = __builtin_amdgcn_mfma_f32_16x16x32_bf16(fah[m], fbl[n], acc[m][n], 0, 0, 0);
      }
  }
#pragma unroll
  for (int m = 0; m < 4; ++m)
#pragma unroll
    for (int i = 0; i < 4; ++i) {
      int row = m0 + wr * 64 + m * 16 + lg * 4 + i;
#pragma unroll
      for (int n = 0; n < 4; ++n) {
        int col = n0 + wc * 64 + n * 16 + lx;
        C[(size_t)row * 512 + col] = acc[m][n][i] + bias[col];
      }
    }
}

// ---------------------------------------------------------------------------
// LayerNorm with residual + bf16 copy + FUSED gate top-2.
// ---------------------------------------------------------------------------
__global__ __launch_bounds__(256) void ln_res_gate(const float* __restrict__ a,
                                                   const float* __restrict__ b,
                                                   const float* __restrict__ g,
                                                   const float* __restrict__ beta,
                                                   const float* __restrict__ Wg,
                                                   float* __restrict__ out,
                                                   u16* __restrict__ obf,
                                                   float* __restrict__ gp,
                                                   int* __restrict__ tope) {
  int n = blockIdx.x * 4 + (threadIdx.x >> 6);
  int lane = threadIdx.x & 63;
  float v[8];
  float s = 0.f;
#pragma unroll
  for (int i = 0; i < 8; ++i) {
    int d = lane + 64 * i;
    v[i] = a[(size_t)n * D_ + d] + b[(size_t)n * D_ + d];
    s += v[i];
  }
#pragma unroll
  for (int m = 32; m; m >>= 1) s += __shfl_xor(s, m);
  float mean = s * (1.f / D_);
  float s2 = 0.f;
#pragma unroll
  for (int i = 0; i < 8; ++i) { float t = v[i] - mean; s2 += t * t; }
#pragma unroll
  for (int m = 32; m; m >>= 1) s2 += __shfl_xor(s2, m);
  float r = rsqrtf(s2 * (1.f / D_) + 1e-5f);
  float p[E_] = {};
#pragma unroll
  for (int i = 0; i < 8; ++i) {
    int d = lane + 64 * i;
    float val = (v[i] - mean) * r * g[d] + beta[d];
    out[(size_t)n * D_ + d] = val;
    obf[(size_t)n * D_ + d] = f2bf(val);
    const float* wr = &Wg[(size_t)d * E_];
#pragma unroll
    for (int e = 0; e < E_; ++e) p[e] += val * wr[e];
  }
#pragma unroll
  for (int e = 0; e < E_; ++e)
#pragma unroll
    for (int m = 32; m; m >>= 1) p[e] += __shfl_xor(p[e], m);
  if (lane == 0) {
    float mx = p[0];
#pragma unroll
    for (int e = 1; e < E_; ++e) mx = fmaxf(mx, p[e]);
    float q[E_];
#pragma unroll
    for (int e = 0; e < E_; ++e) q[e] = expf(p[e] - mx);
    int e1 = 0;
#pragma unroll
    for (int e = 1; e < E_; ++e) if (q[e] > q[e1]) e1 = e;
    int e2 = (e1 == 0) ? 1 : 0;
#pragma unroll
    for (int e = 0; e < E_; ++e) if (e != e1 && q[e] > q[e2]) e2 = e;
    float denom = q[e1] + q[e2];
    gp[n * 2] = q[e1] / denom;
    gp[n * 2 + 1] = q[e2] / denom;
    tope[n] = e1 | (e2 << 8);
  }
}

__global__ __launch_bounds__(256) void ln2_final(const float* __restrict__ x,
                                                 const u16* __restrict__ mp,
                                                 const float* __restrict__ g,
                                                 const float* __restrict__ beta,
                                                 float* __restrict__ out) {
  int n = blockIdx.x * 4 + (threadIdx.x >> 6);
  int lane = threadIdx.x & 63;
  float v[8];
  float s = 0.f;
#pragma unroll
  for (int i = 0; i < 8; ++i) {
    int d = lane + 64 * i;
    v[i] = x[(size_t)n * D_ + d] + bf2f(mp[(size_t)(2 * n) * D_ + d]) +
           bf2f(mp[(size_t)(2 * n + 1) * D_ + d]);
    s += v[i];
  }
#pragma unroll
  for (int m = 32; m; m >>= 1) s += __shfl_xor(s, m);
  float mean = s * (1.f / D_);
  float s2 = 0.f;
#pragma unroll
  for (int i = 0; i < 8; ++i) { float t = v[i] - mean; s2 += t * t; }
#pragma unroll
  for (int m = 32; m; m >>= 1) s2 += __shfl_xor(s2, m);
  float r = rsqrtf(s2 * (1.f / D_) + 1e-5f);
#pragma unroll
  for (int i = 0; i < 8; ++i) {
    int d = lane + 64 * i;
    out[(size_t)n * D_ + d] = (v[i] - mean) * r * g[d] + beta[d];
  }
}

// ---------------------------------------------------------------------------
// bf16 MFMA MoE GEMM, 64x128 tile, BK=32, 4 waves (each 64x32 out).
// Flat grid, expert = blockIdx & 7 -> expert pinned to one XCD.
// ---------------------------------------------------------------------------
template <int MODE>
__global__ __launch_bounds__(256) void moe_mfma(const u16* __restrict__ Abase,
                                                const u16* __restrict__ Wt,
                                                const float* __restrict__ bias,
                                                const float* __restrict__ gp,
                                                u16* __restrict__ outp,
                                                const int* __restrict__ cnt,
                                                const int* __restrict__ lst) {
  constexpr int K  = MODE ? 1024 : 512;
  constexpr int Nn = MODE ? 512 : 1024;
  constexpr int NT = Nn / 128;
  constexpr int NI = K / 32;
  int fidx = blockIdx.x;
  int e = fidx & 7;
  int r = fidx >> 3;
  int nt = r % NT;
  int mt = r / NT;
  int c = cnt[e];
  int m0 = mt * 64;
  if (m0 >= c) return;
  int off = 0;
#pragma unroll
  for (int i = 0; i < E_; ++i) if (i < e) off += cnt[i];
  int n0 = nt * 128;
  __shared__ u16 As[64][40];
  __shared__ u16 Bs[128][40];
  int tid = threadIdx.x;
  int w = tid >> 6, l = tid & 63;
  int lg = l >> 4, lx = l & 15;
  int arow = tid >> 2, aseg = (tid & 3) * 8;
  int brow = tid >> 1, bseg = (tid & 1) * 16;
  int ar = m0 + arow; if (ar >= c) ar = c - 1;
  const u16* Ap;
  if (MODE == 0) Ap = Abase + (size_t)(lst[e * N_ + ar] >> 1) * 512 + aseg;
  else           Ap = Abase + (size_t)(off + ar) * 1024 + aseg;
  const u16* Bp = Wt + (size_t)e * K * Nn + (size_t)(n0 + brow) * K + bseg;

  f32x4 acc[4][2];
#pragma unroll
  for (int m = 0; m < 4; ++m)
#pragma unroll
    for (int n = 0; n < 2; ++n) acc[m][n] = (f32x4){0.f, 0.f, 0.f, 0.f};

  short8 pa  = *(const short8*)&Ap[0];
  short8 pb0 = *(const short8*)&Bp[0];
  short8 pb1 = *(const short8*)&Bp[8];
  for (int kk = 0; kk < NI; ++kk) {
    __syncthreads();
    *(short8*)&As[arow][aseg] = pa;
    *(short8*)&Bs[brow][bseg] = pb0;
    *(short8*)&Bs[brow][bseg + 8] = pb1;
    __syncthreads();
    if (kk + 1 < NI) {
      int ko = (kk + 1) * 32;
      pa  = *(const short8*)&Ap[ko];
      pb0 = *(const short8*)&Bp[ko];
      pb1 = *(const short8*)&Bp[ko + 8];
    }
    short8 af[4], bf[2];
#pragma unroll
    for (int m = 0; m < 4; ++m)
      af[m] = *(const short8*)&As[m * 16 + lx][lg * 8];
#pragma unroll
    for (int n = 0; n < 2; ++n)
      bf[n] = *(const short8*)&Bs[w * 32 + n * 16 + lx][lg * 8];
#pragma unroll
    for (int m = 0; m < 4; ++m)
#pragma unroll
      for (int n = 0; n < 2; ++n)
        acc[m][n] = __builtin_amdgcn_mfma_f32_16x16x32_bf16(af[m], bf[n], acc[m][n], 0, 0, 0);
  }
#pragma unroll
  for (int m = 0; m < 4; ++m)
#pragma unroll
    for (int i = 0; i < 4; ++i) {
      int rr = m0 + m * 16 + lg * 4 + i;
      if (rr < c) {
#pragma unroll
        for (int n = 0; n < 2; ++n) {
          int col = n0 + w * 32 + n * 16 + lx;
          float val = acc[m][n][i] + bias[e * Nn + col];
          if (MODE == 0) {
            outp[(size_t)(off + rr) * 1024 + col] = f2bf(fmaxf(val, 0.f));
          } else {
            int p = lst[e * N_ + rr];
            outp[(size_t)p * 512 + col] = f2bf(gp[p] * val);
          }
        }
      }
    }
}

// ---------------------------------------------------------------------------
extern "C" void kernel_launch(void* const* d_in, const int* in_sizes, int n_in,
                              void* d_out, int out_size, void* d_ws, size_t ws_size,
                              hipStream_t stream) {
  const float* src  = (const float*)d_in[0];
  const float* cosb = (const float*)d_in[1];
  const float* sinb = (const float*)d_in[2];
  const float* Wq   = (const float*)d_in[3];
  const float* bq   = (const float*)d_in[4];
  const float* Wk   = (const float*)d_in[5];
  const float* bk   = (const float*)d_in[6];
  const float* Wv   = (const float*)d_in[7];
  const float* bv   = (const float*)d_in[8];
  const float* Wo   = (const float*)d_in[9];
  const float* bo   = (const float*)d_in[10];
  const float* ln1g = (const float*)d_in[11];
  const float* ln1b = (const float*)d_in[12];
  const float* ln2g = (const float*)d_in[13];
  const float* ln2b = (const float*)d_in[14];
  const float* Wg   = (const float*)d_in[15];
  const float* W1   = (const float*)d_in[16];
  const float* B1   = (const float*)d_in[17];
  const float* W2   = (const float*)d_in[18];
  const float* B2   = (const float*)d_in[19];
  float* out = (float*)d_out;
  char* wsb = (char*)d_ws;

  const size_t MB1 = 1u << 20;
  u16* sh   = (u16*)(wsb + 0 * MB1);      // src hi  [0,4M)   ; later ch, then mp
  u16* sl   = (u16*)(wsb + 4 * MB1);      // src lo  [4,8M)   ; later cl
  u16* qhb  = (u16*)(wsb + 8 * MB1);      // [8,12M)          ; later hbf part
  u16* qlb  = (u16*)(wsb + 12 * MB1);
  u16* khb  = (u16*)(wsb + 16 * MB1);
  u16* klb  = (u16*)(wsb + 20 * MB1);
  u16* vbuf = (u16*)(wsb + 24 * MB1);     // [24,28M)
  u16* poh  = (u16*)(wsb + 28 * MB1);     // [28,36M) attn partial hi ; later aob f32, then W2t
  u16* pol  = (u16*)(wsb + 36 * MB1);     // [36,44M) attn partial lo ; later xb f32
  float* pml = (float*)(wsb + 44 * MB1);  // [44,44.5M)       ; later xbf
  float* aob = (float*)(wsb + 28 * MB1);  // [28,36M)
  float* xb  = (float*)(wsb + 36 * MB1);  // [36,44M)
  u16* xbf   = (u16*)(wsb + 44 * MB1);    // [44,48M)
  u16* Wqkv_hi = (u16*)(wsb + 48 * MB1);              // 1.5MB
  u16* Wqkv_lo = (u16*)(wsb + 48 * MB1 + 1572864);    // 1.5MB
  u16* Wo_hi   = (u16*)(wsb + 48 * MB1 + 3145728);    // 0.5MB
  u16* Wo_lo   = (u16*)(wsb + 48 * MB1 + 3670016);    // 0.5MB
  u16* W1t     = (u16*)(wsb + 52 * MB1);  // [52,60M)
  u16* W2t     = (u16*)(wsb + 28 * MB1);  // [28,36M) — written after ln_res_gate (aob dead)
  float* gpb   = (float*)(wsb + 60 * MB1);                 // 32 KB
  int* cnt     = (int*)(wsb + 60 * MB1 + 32768);           // 64 B
  int* lst     = (int*)(wsb + 60 * MB1 + 32768 + 64);      // 128 KB
  int* tope    = (int*)(wsb + 60 * MB1 + 32768 + 64 + 131072);  // 16 KB
  u16* ch  = sh;                          // ctx hi aliases src-split (dead)
  u16* cl  = sl;
  u16* hbf = (u16*)(wsb + 8 * MB1);       // [8,24M) aliases q/k (dead after attn)
  u16* mp  = (u16*)(wsb + 0 * MB1);       // [0,8M)  aliases ch/cl (dead after wo)

  dim3 blk(256);
  // Weight splits + src split in ONE launch
  wsplit_all<<<dim3(8, 8, 20), blk, 0, stream>>>(Wq, Wk, Wv, Wo, src,
                                                 Wqkv_hi, Wqkv_lo, Wo_hi, Wo_lo,
                                                 sh, sl);
  // QKV + RoPE fused (split-bf16; V-blocks 2-product), XCD-pinned flat grid
  qkv_mfma<<<dim3(384), blk, 0, stream>>>(sh, sl, Wqkv_hi, Wqkv_lo, bq, bk, bv,
                                          cosb, sinb, qhb, qlb, khb, klb, vbuf);
  // Attention, KV-split=2, XCD-pinned slabs, QT=128, KT=128
  attn_mfma2<<<dim3(512), dim3(512), 0, stream>>>(qhb, qlb, khb, klb, vbuf, poh, pol, pml);
  merge_attn2<<<dim3(8192), blk, 0, stream>>>(poh, pol, pml, ch, cl);
  // Wo projection (split-bf16), XCD-pinned flat grid
  wo_mfma<<<dim3(128), blk, 0, stream>>>(ch, cl, Wo_hi, Wo_lo, bo, aob);
  // LN1 + fused gate top-2
  ln_res_gate<<<dim3(1024), blk, 0, stream>>>(src, aob, ln1g, ln1b, Wg, xb, xbf, gpb, tope);
  // MoE weight transposes + ordered routing in ONE launch
  wtrans_all<<<dim3(16, 16, 17), blk, 0, stream>>>(W1, W2, W1t, W2t, tope, cnt, lst);
  // Sparse MoE expert GEMMs — 64x128 tiles, expert pinned to XCD
  moe_mfma<0><<<dim3(8 * 8 * 64), blk, 0, stream>>>(xbf, W1t, B1, gpb, hbf, cnt, lst);
  moe_mfma<1><<<dim3(8 * 4 * 64), blk, 0, stream>>>(hbf, W2t, B2, gpb, mp, cnt, lst);
  ln2_final<<<dim3(1024), blk, 0, stream>>>(xb, mp, ln2g, ln2b, out);
}

// Round 20
// 204.773 us; speedup vs baseline: 1.0678x; 1.0010x over previous
//
#include <hip/hip_runtime.h>
#include <math.h>

// Shapes (fixed)
#define S_  2048
#define B_  2
#define D_  512
#define H_  8
#define DH_ 64
#define E_  8
#define F_  1024
#define N_  4096   // S_*B_
#define NPAIR_ 8192

typedef __attribute__((ext_vector_type(4))) float f32x4;
typedef __attribute__((ext_vector_type(8))) short short8;
typedef __attribute__((ext_vector_type(4))) short short4v;
typedef unsigned short u16;

__device__ __forceinline__ u16 f2bf(float f) {
  unsigned u = __builtin_bit_cast(unsigned, f);
  u += 0x7fffu + ((u >> 16) & 1u);
  return (u16)(u >> 16);
}
__device__ __forceinline__ float bf2f(u16 h) {
  unsigned u = ((unsigned)h) << 16;
  return __builtin_bit_cast(float, u);
}

// ---------------------------------------------------------------------------
// Weight transpose + split (device body): Whi/Wlo[n][k] = split(W[k][n]).
// ---------------------------------------------------------------------------
__device__ __forceinline__ void wsplit_body(const float* __restrict__ W,
                                            u16* __restrict__ Whi,
                                            u16* __restrict__ Wlo,
                                            int Nn, int K, int kb, int nb) {
  __shared__ u16 Th[64][72];
  __shared__ u16 Tl[64][72];
  int r = threadIdx.x >> 2, c0 = (threadIdx.x & 3) * 16;
  const float* wp = &W[(size_t)(kb + r) * Nn + nb + c0];
#pragma unroll
  for (int c = 0; c < 16; c += 4) {
    float4 t = *(const float4*)&wp[c];
    float f[4] = {t.x, t.y, t.z, t.w};
#pragma unroll
    for (int j = 0; j < 4; ++j) {
      u16 a = f2bf(f[j]);
      Th[r][c0 + c + j] = a;
      Tl[r][c0 + c + j] = f2bf(f[j] - bf2f(a));
    }
  }
  __syncthreads();
  short8 h0, h1, l0, l1;
#pragma unroll
  for (int j = 0; j < 8; ++j) {
    h0[j] = (short)Th[c0 + j][r];     h1[j] = (short)Th[c0 + 8 + j][r];
    l0[j] = (short)Tl[c0 + j][r];     l1[j] = (short)Tl[c0 + 8 + j][r];
  }
  size_t ob = (size_t)(nb + r) * K + kb + c0;
  *(short8*)&Whi[ob] = h0;  *(short8*)&Whi[ob + 8] = h1;
  *(short8*)&Wlo[ob] = l0;  *(short8*)&Wlo[ob + 8] = l1;
}

// One launch: Wq/Wk/Wv/Wo splits (z<4) + src split (z>=4). grid (8,8,20).
__global__ __launch_bounds__(256) void wsplit_all(const float* __restrict__ Wq,
                                                  const float* __restrict__ Wk,
                                                  const float* __restrict__ Wv,
                                                  const float* __restrict__ Wo,
                                                  const float* __restrict__ src,
                                                  u16* __restrict__ Wqkv_hi,
                                                  u16* __restrict__ Wqkv_lo,
                                                  u16* __restrict__ Wo_hi,
                                                  u16* __restrict__ Wo_lo,
                                                  u16* __restrict__ sh,
                                                  u16* __restrict__ sl) {
  int z = blockIdx.z;
  if (z < 4) {
    const float* W = (z == 0) ? Wq : (z == 1) ? Wk : (z == 2) ? Wv : Wo;
    u16* Whi = (z == 3) ? Wo_hi : Wqkv_hi + (size_t)z * 512 * 512;
    u16* Wlo = (z == 3) ? Wo_lo : Wqkv_lo + (size_t)z * 512 * 512;
    wsplit_body(W, Whi, Wlo, 512, 512, blockIdx.y * 64, blockIdx.x * 64);
  } else {
    int idx = (z - 4) * 64 + blockIdx.y * 8 + blockIdx.x;
    size_t i = ((size_t)idx * 256 + threadIdx.x) * 8;
    float f[8];
    *(float4*)&f[0] = *(const float4*)&src[i];
    *(float4*)&f[4] = *(const float4*)&src[i + 4];
    short8 h, l;
#pragma unroll
    for (int j = 0; j < 8; ++j) {
      u16 a = f2bf(f[j]);
      h[j] = (short)a;
      l[j] = (short)f2bf(f[j] - bf2f(a));
    }
    *(short8*)&sh[i] = h;
    *(short8*)&sl[i] = l;
  }
}

// ---------------------------------------------------------------------------
// MoE weight transpose (W1+W2) + route_build in ONE launch.
// grid (16,16,17): z<8 W1 expert z; z<16 W2 expert z-8; z==16 route (8 blocks).
// ---------------------------------------------------------------------------
__global__ __launch_bounds__(256) void wtrans_all(const float* __restrict__ W1,
                                                  const float* __restrict__ W2,
                                                  u16* __restrict__ W1t,
                                                  u16* __restrict__ W2t,
                                                  const int* __restrict__ tope,
                                                  int* __restrict__ cnt,
                                                  int* __restrict__ lst) {
  int z = blockIdx.z;
  __shared__ u16 T[64][72];
  __shared__ int wsum[4];
  __shared__ int basem;
  if (z == 16) {
    if (blockIdx.x >= 8 || blockIdx.y != 0) return;
    int e = blockIdx.x;
    int tid = threadIdx.x;
    int w = tid >> 6, lane = tid & 63;
    if (tid == 0) basem = 0;
    __syncthreads();
    for (int c0 = 0; c0 < N_; c0 += 256) {
      int n = c0 + tid;
      int te = tope[n];
      int e1 = te & 0xff, e2 = (te >> 8) & 0xff;
      bool m2 = (e2 == e);
      bool flag = (e1 == e) || m2;
      unsigned long long mask = __ballot(flag);
      int wpre = __popcll(mask & ((1ull << lane) - 1ull));
      if (lane == 0) wsum[w] = __popcll(mask);
      __syncthreads();
      int woff = 0;
      for (int i = 0; i < w; ++i) woff += wsum[i];
      int total = wsum[0] + wsum[1] + wsum[2] + wsum[3];
      if (flag) lst[e * N_ + basem + woff + wpre] = n * 2 + (m2 ? 1 : 0);
      __syncthreads();
      if (tid == 0) basem += total;
      __syncthreads();
    }
    if (tid == 0) cnt[e] = basem;
    return;
  }
  const float* W;
  u16* Wt;
  int K, Nn, e;
  if (z < 8) {
    if (blockIdx.y >= 8) return;
    W = W1; Wt = W1t; K = 512; Nn = 1024; e = z;
  } else {
    if (blockIdx.x >= 8) return;
    W = W2; Wt = W2t; K = 1024; Nn = 512; e = z - 8;
  }
  size_t eo = (size_t)e * K * Nn;
  int kb = blockIdx.y * 64, nb = blockIdx.x * 64;
  int r = threadIdx.x >> 2, c0 = (threadIdx.x & 3) * 16;
  const float* wp = &W[eo + (size_t)(kb + r) * Nn + nb + c0];
#pragma unroll
  for (int c = 0; c < 16; c += 4) {
    float4 t = *(const float4*)&wp[c];
    T[r][c0 + c + 0] = f2bf(t.x);
    T[r][c0 + c + 1] = f2bf(t.y);
    T[r][c0 + c + 2] = f2bf(t.z);
    T[r][c0 + c + 3] = f2bf(t.w);
  }
  __syncthreads();
  short8 s0, s1;
#pragma unroll
  for (int j = 0; j < 8; ++j) {
    s0[j] = (short)T[c0 + j][r];
    s1[j] = (short)T[c0 + 8 + j][r];
  }
  *(short8*)&Wt[eo + (size_t)(nb + r) * K + kb + c0] = s0;
  *(short8*)&Wt[eo + (size_t)(nb + r) * K + kb + c0 + 8] = s1;
}

// ---------------------------------------------------------------------------
// Fused QKV split-bf16 MFMA GEMM + RoPE. M=4096, N=1536, K=512.
// Flat XCD-pinned grid (384 = 8 xcd x 4 m x 12 n).
// V-blocks (nt>=8): B-lo term skipped (output is bf16-quantized anyway).
// ---------------------------------------------------------------------------
__global__ __launch_bounds__(256) void qkv_mfma(const u16* __restrict__ Ah_g,
                                                const u16* __restrict__ Al_g,
                                                const u16* __restrict__ Bh_g,
                                                const u16* __restrict__ Bl_g,
                                                const float* __restrict__ bq,
                                                const float* __restrict__ bk,
                                                const float* __restrict__ bv,
                                                const float* __restrict__ cosb,
                                                const float* __restrict__ sinb,
                                                u16* __restrict__ qh, u16* __restrict__ ql,
                                                u16* __restrict__ kh, u16* __restrict__ kl,
                                                u16* __restrict__ vb) {
  __shared__ u16 Ah[128][40], Al[128][40], Bh[128][40], Bl[128][40];
  int tid = threadIdx.x;
  int w = tid >> 6, l = tid & 63;
  int wr = w >> 1, wc = w & 1;
  int lg = l >> 4, lx = l & 15;
  int f = blockIdx.x;
  int xcd = f & 7, rr = f >> 3;        // rr 0..47
  int mt = xcd * 4 + (rr & 3);         // 0..31, m-slab pinned to XCD
  int nt = rr >> 2;                    // 0..11
  bool qk = (nt < 8);                  // q/k blocks: full 3-product precision
  int m0 = mt * 128, n0 = nt * 128;
  int sr = tid >> 1, s16 = (tid & 1) * 16;
  const u16* Aph = Ah_g + (size_t)(m0 + sr) * 512;
  const u16* Apl = Al_g + (size_t)(m0 + sr) * 512;
  const u16* Bph = Bh_g + (size_t)(n0 + sr) * 512;
  const u16* Bpl = Bl_g + (size_t)(n0 + sr) * 512;
  f32x4 acc[4][4];
#pragma unroll
  for (int m = 0; m < 4; ++m)
#pragma unroll
    for (int n = 0; n < 4; ++n) acc[m][n] = (f32x4){0.f, 0.f, 0.f, 0.f};
  short8 ah0 = *(const short8*)&Aph[s16];
  short8 ah1 = *(const short8*)&Aph[s16 + 8];
  short8 al0 = *(const short8*)&Apl[s16];
  short8 al1 = *(const short8*)&Apl[s16 + 8];
  short8 bh0 = *(const short8*)&Bph[s16];
  short8 bh1 = *(const short8*)&Bph[s16 + 8];
  short8 bl0, bl1;
  if (qk) {
    bl0 = *(const short8*)&Bpl[s16];
    bl1 = *(const short8*)&Bpl[s16 + 8];
  }
  for (int k0 = 0; k0 < 512; k0 += 32) {
    __syncthreads();
    *(short8*)&Ah[sr][s16] = ah0; *(short8*)&Ah[sr][s16 + 8] = ah1;
    *(short8*)&Al[sr][s16] = al0; *(short8*)&Al[sr][s16 + 8] = al1;
    *(short8*)&Bh[sr][s16] = bh0; *(short8*)&Bh[sr][s16 + 8] = bh1;
    if (qk) {
      *(short8*)&Bl[sr][s16] = bl0; *(short8*)&Bl[sr][s16 + 8] = bl1;
    }
    __syncthreads();
    if (k0 + 32 < 512) {
      int ko = k0 + 32 + s16;
      ah0 = *(const short8*)&Aph[ko]; ah1 = *(const short8*)&Aph[ko + 8];
      al0 = *(const short8*)&Apl[ko]; al1 = *(const short8*)&Apl[ko + 8];
      bh0 = *(const short8*)&Bph[ko]; bh1 = *(const short8*)&Bph[ko + 8];
      if (qk) {
        bl0 = *(const short8*)&Bpl[ko]; bl1 = *(const short8*)&Bpl[ko + 8];
      }
    }
    short8 fah[4], fal[4], fbh[4], fbl[4];
#pragma unroll
    for (int m = 0; m < 4; ++m) {
      fah[m] = *(const short8*)&Ah[wr * 64 + m * 16 + lx][lg * 8];
      fal[m] = *(const short8*)&Al[wr * 64 + m * 16 + lx][lg * 8];
    }
#pragma unroll
    for (int n = 0; n < 4; ++n) {
      fbh[n] = *(const short8*)&Bh[wc * 64 + n * 16 + lx][lg * 8];
    }
    if (qk) {
#pragma unroll
      for (int n = 0; n < 4; ++n)
        fbl[n] = *(const short8*)&Bl[wc * 64 + n * 16 + lx][lg * 8];
    }
#pragma unroll
    for (int m = 0; m < 4; ++m)
#pragma unroll
      for (int n = 0; n < 4; ++n) {
        acc[m][n] = __builtin_amdgcn_mfma_f32_16x16x32_bf16(fah[m], fbh[n], acc[m][n], 0, 0, 0);
        acc[m][n] = __builtin_amdgcn_mfma_f32_16x16x32_bf16(fal[m], fbh[n], acc[m][n], 0, 0, 0);
      }
    if (qk) {
#pragma unroll
      for (int m = 0; m < 4; ++m)
#pragma unroll
        for (int n = 0; n < 4; ++n)
          acc[m][n] = __builtin_amdgcn_mfma_f32_16x16x32_bf16(fah[m], fbl[n], acc[m][n], 0, 0, 0);
    }
  }
  // ---- epilogue ----
  int tcolbase = n0 + wc * 64;
  int tsel = tcolbase >> 9;             // 0=q, 1=k, 2=v
  int hbase = tcolbase & 511;
  const float* bias = (tsel == 0) ? bq : (tsel == 1) ? bk : bv;
  if (tsel == 2) {
#pragma unroll
    for (int m = 0; m < 4; ++m)
#pragma unroll
      for (int i = 0; i < 4; ++i) {
        int row = m0 + wr * 64 + m * 16 + lg * 4 + i;
#pragma unroll
        for (int n = 0; n < 4; ++n) {
          int col = hbase + n * 16 + lx;
          vb[(size_t)row * 512 + col] = f2bf(acc[m][n][i] + bias[col]);
        }
      }
  } else {
    u16* oh = tsel ? kh : qh;
    u16* ol = tsel ? kl : ql;
    float qsc = tsel ? 1.f : 0.125f;
#pragma unroll
    for (int m = 0; m < 4; ++m)
#pragma unroll
      for (int i = 0; i < 4; ++i) {
        int row = m0 + wr * 64 + m * 16 + lg * 4 + i;
        int s = row >> 1;
#pragma unroll
        for (int n = 0; n < 2; ++n) {
          int dln = n * 16 + lx;
          float c  = cosb[s * 64 + dln];
          float sn = sinb[s * 64 + dln];
          float a  = acc[m][n][i]     + bias[hbase + dln];
          float b2 = acc[m][n + 2][i] + bias[hbase + dln + 32];
          float ra = (a * c - b2 * sn) * qsc;
          float rb = (b2 * c + a * sn) * qsc;
          size_t ix = (size_t)row * 512 + hbase + dln;
          u16 rah = f2bf(ra);
          oh[ix] = rah; ol[ix] = f2bf(ra - bf2f(rah));
          u16 rbh = f2bf(rb);
          oh[ix + 32] = rbh; ol[ix + 32] = f2bf(rb - bf2f(rbh));
        }
      }
  }
}

// ---------------------------------------------------------------------------
// MFMA flash attention, KV-split=2, XCD-pinned (b,h,kvh) slabs, QT=128.
// KT=128: one softmax pass per 128 kv rows; PV in two 64-kv sub-chunks.
// ---------------------------------------------------------------------------
__global__ __launch_bounds__(512, 4) void attn_mfma2(const u16* __restrict__ qh,
                                                     const u16* __restrict__ ql,
                                                     const u16* __restrict__ kh,
                                                     const u16* __restrict__ kl,
                                                     const u16* __restrict__ vbuf,
                                                     u16* __restrict__ poh,
                                                     u16* __restrict__ pol,
                                                     float* __restrict__ pml) {
  __shared__ u16 Khi[128][72];
  __shared__ u16 Klo[128][72];
  __shared__ u16 Vt[64][136];          // [d][kv 0..127]
  __shared__ unsigned P2[8][16][32];   // per-wave P chunk (64 kv)
  int tid = threadIdx.x;
  int w = tid >> 6, l = tid & 63;      // w 0..7
  int lg = l >> 4, lx = l & 15;
  int f = blockIdx.x;                  // 0..511
  int xcd = f & 7, j = f >> 3;         // j 0..63
  int slab = xcd + 8 * (j & 3);        // 0..31 : all qt of a slab share an XCD
  int qt = j >> 2;                     // 0..15 (128-row q tiles)
  int bh = slab >> 1, kvh = slab & 1;
  int b = bh >> 3, h = bh & 7;

  short8 qfh[2], qfl[2];
  {
    int qrow = qt * 128 + w * 16 + lx;
    size_t qo = (size_t)(qrow * 2 + b) * 512 + h * 64 + lg * 8;
    qfh[0] = *(const short8*)&qh[qo];
    qfh[1] = *(const short8*)&qh[qo + 32];
    qfl[0] = *(const short8*)&ql[qo];
    qfl[1] = *(const short8*)&ql[qo + 32];
  }

  f32x4 o_acc[4];
#pragma unroll
  for (int dg = 0; dg < 4; ++dg) o_acc[dg] = (f32x4){0.f, 0.f, 0.f, 0.f};
  float m_run = -1e30f, l_run = 0.f;

  int kvr = tid >> 2, ds4 = (tid & 3) * 16;   // K: 128 rows x 64, 16 el/thread
  int kvc = tid & 127, dsg = (tid >> 7) * 16; // V: transpose, 16 el/thread
  int psw = (lx & 7) << 2;                    // P2 bank swizzle

  short8 rkh0, rkh1, rkl0, rkl1, rv0, rv1;
  {
    int t0 = kvh * 1024;
    size_t ko = (size_t)((t0 + kvr) * 2 + b) * 512 + h * 64 + ds4;
    rkh0 = *(const short8*)&kh[ko]; rkh1 = *(const short8*)&kh[ko + 8];
    rkl0 = *(const short8*)&kl[ko]; rkl1 = *(const short8*)&kl[ko + 8];
    size_t vo = (size_t)((t0 + kvc) * 2 + b) * 512 + h * 64 + dsg;
    rv0 = *(const short8*)&vbuf[vo]; rv1 = *(const short8*)&vbuf[vo + 8];
  }

  for (int it = 0; it < 8; ++it) {
    __syncthreads();
    *(short8*)&Khi[kvr][ds4]     = rkh0;
    *(short8*)&Khi[kvr][ds4 + 8] = rkh1;
    *(short8*)&Klo[kvr][ds4]     = rkl0;
    *(short8*)&Klo[kvr][ds4 + 8] = rkl1;
#pragma unroll
    for (int c = 0; c < 8; ++c) {
      Vt[dsg + c][kvc]     = (u16)rv0[c];
      Vt[dsg + 8 + c][kvc] = (u16)rv1[c];
    }
    __syncthreads();
    if (it + 1 < 8) {
      int t0 = kvh * 1024 + (it + 1) * 128;
      size_t ko = (size_t)((t0 + kvr) * 2 + b) * 512 + h * 64 + ds4;
      rkh0 = *(const short8*)&kh[ko]; rkh1 = *(const short8*)&kh[ko + 8];
      rkl0 = *(const short8*)&kl[ko]; rkl1 = *(const short8*)&kl[ko + 8];
      size_t vo = (size_t)((t0 + kvc) * 2 + b) * 512 + h * 64 + dsg;
      rv0 = *(const short8*)&vbuf[vo]; rv1 = *(const short8*)&vbuf[vo + 8];
    }

    // ---- QK^T, swapped: D[kv][q], kv = 16cg+4lg+i (cg 0..7) ----
    f32x4 sc[8];
#pragma unroll
    for (int cg = 0; cg < 8; ++cg) {
      short8 kf0 = *(const short8*)&Khi[cg * 16 + lx][lg * 8];
      short8 kf1 = *(const short8*)&Khi[cg * 16 + lx][32 + lg * 8];
      short8 kg0 = *(const short8*)&Klo[cg * 16 + lx][lg * 8];
      short8 kg1 = *(const short8*)&Klo[cg * 16 + lx][32 + lg * 8];
      f32x4 a = (f32x4){0.f, 0.f, 0.f, 0.f};
      a = __builtin_amdgcn_mfma_f32_16x16x32_bf16(kf0, qfh[0], a, 0, 0, 0);
      a = __builtin_amdgcn_mfma_f32_16x16x32_bf16(kf1, qfh[1], a, 0, 0, 0);
      a = __builtin_amdgcn_mfma_f32_16x16x32_bf16(kf0, qfl[0], a, 0, 0, 0);
      a = __builtin_amdgcn_mfma_f32_16x16x32_bf16(kf1, qfl[1], a, 0, 0, 0);
      a = __builtin_amdgcn_mfma_f32_16x16x32_bf16(kg0, qfh[0], a, 0, 0, 0);
      a = __builtin_amdgcn_mfma_f32_16x16x32_bf16(kg1, qfh[1], a, 0, 0, 0);
      sc[cg] = a;
    }

    // ---- ONE in-register softmax over all 128 kv for q = lx ----
    float tm = sc[0][0];
#pragma unroll
    for (int cg = 0; cg < 8; ++cg)
#pragma unroll
      for (int i = 0; i < 4; ++i) tm = fmaxf(tm, sc[cg][i]);
    tm = fmaxf(tm, __shfl_xor(tm, 16));
    tm = fmaxf(tm, __shfl_xor(tm, 32));
    float mn = fmaxf(m_run, tm);
    float corr = __expf(m_run - mn);
    m_run = mn;
    float ts = 0.f;
#pragma unroll
    for (int cg = 0; cg < 8; ++cg)
#pragma unroll
      for (int i = 0; i < 4; ++i) {
        float pv = __expf(sc[cg][i] - mn);
        sc[cg][i] = pv;
        ts += pv;
      }
    ts += __shfl_xor(ts, 16);
    ts += __shfl_xor(ts, 32);
    l_run = l_run * corr + ts;
#pragma unroll
    for (int dg = 0; dg < 4; ++dg) o_acc[dg] *= corr;

    // ---- PV in two 64-kv chunks, reusing P2 (wave-local) ----
#pragma unroll
    for (int ch = 0; ch < 2; ++ch) {
#pragma unroll
      for (int cg = 0; cg < 4; ++cg)
#pragma unroll
        for (int t = 0; t < 2; ++t) {
          const f32x4& s4 = sc[4 * ch + cg];
          unsigned dw = (unsigned)f2bf(s4[2 * t]) |
                        ((unsigned)f2bf(s4[2 * t + 1]) << 16);
          P2[w][lx][(8 * cg + 2 * lg + t) ^ psw] = dw;
        }
      short8 pf0 = *(const short8*)&P2[w][lx][(4 * lg) ^ psw];
      short8 pf1 = *(const short8*)&P2[w][lx][(16 + 4 * lg) ^ psw];
#pragma unroll
      for (int dg = 0; dg < 4; ++dg) {
        short8 v0 = *(const short8*)&Vt[dg * 16 + lx][ch * 64 + lg * 8];
        short8 v1 = *(const short8*)&Vt[dg * 16 + lx][ch * 64 + 32 + lg * 8];
        o_acc[dg] = __builtin_amdgcn_mfma_f32_16x16x32_bf16(v0, pf0, o_acc[dg], 0, 0, 0);
        o_acc[dg] = __builtin_amdgcn_mfma_f32_16x16x32_bf16(v1, pf1, o_acc[dg], 0, 0, 0);
      }
    }
  }

  // ---- epilogue: lane holds ctx^T[d=16dg+4lg+i][q=lx] ----
  {
    int qrow = qt * 128 + w * 16 + lx;
    int row2 = qrow * 2 + b;
    size_t base = (size_t)kvh * ((size_t)N_ * D_) + (size_t)row2 * 512 + h * 64;
#pragma unroll
    for (int dg = 0; dg < 4; ++dg)
#pragma unroll
      for (int i = 0; i < 4; ++i) {
        int d = dg * 16 + 4 * lg + i;
        float val = o_acc[dg][i];
        u16 hi = f2bf(val);
        poh[base + d] = hi;
        pol[base + d] = f2bf(val - bf2f(hi));
      }
    if (lg == 0) {
      int u = row2 * 8 + h;
      pml[(size_t)kvh * 65536 + u * 2 + 0] = m_run;
      pml[(size_t)kvh * 65536 + u * 2 + 1] = l_run;
    }
  }
}

// Merge the two KV halves -> split-bf16 ctx. Vectorized: 4 el/thread.
__global__ __launch_bounds__(256) void merge_attn2(const u16* __restrict__ poh,
                                                   const u16* __restrict__ pol,
                                                   const float* __restrict__ pml,
                                                   u16* __restrict__ ch,
                                                   u16* __restrict__ cl) {
  int u = blockIdx.x * 4 + (threadIdx.x >> 6);      // 2048 blocks -> u 0..8191
  int lane = threadIdx.x & 63;
  // Each u covers 4 (row,head) units: u4 = u*4 .. u*4+3; lane covers 16 d-quads
  int uu = u * 4 + (lane >> 4);                     // unit 0..32767
  int d0 = (lane & 15) * 4;                         // d quad
  float m0 = pml[uu * 2], l0 = pml[uu * 2 + 1];
  float m1 = pml[65536 + uu * 2], l1 = pml[65536 + uu * 2 + 1];
  float m = fmaxf(m0, m1);
  float e0 = __expf(m0 - m), e1 = __expf(m1 - m);
  float inv = 1.f / (l0 * e0 + l1 * e1);
  int n = uu >> 3, h = uu & 7;
  size_t base = (size_t)n * 512 + h * 64 + d0;
  const size_t PO1 = (size_t)N_ * D_;
  short4v p0h = *(const short4v*)&poh[base];
  short4v p0l = *(const short4v*)&pol[base];
  short4v p1h = *(const short4v*)&poh[PO1 + base];
  short4v p1l = *(const short4v*)&pol[PO1 + base];
  short4v oh, ol;
#pragma unroll
  for (int k = 0; k < 4; ++k) {
    float v0 = bf2f((u16)p0h[k]) + bf2f((u16)p0l[k]);
    float v1 = bf2f((u16)p1h[k]) + bf2f((u16)p1l[k]);
    float val = (v0 * e0 + v1 * e1) * inv;
    u16 hi = f2bf(val);
    oh[k] = (short)hi;
    ol[k] = (short)f2bf(val - bf2f(hi));
  }
  *(short4v*)&ch[base] = oh;
  *(short4v*)&cl[base] = ol;
}

// ---------------------------------------------------------------------------
// Wo projection: split-bf16 MFMA GEMM, M=4096, N=512, K=512, f32 out.
// Flat XCD-pinned grid (128 = 8 xcd x 4 m x 4 n).
// ---------------------------------------------------------------------------
__global__ __launch_bounds__(256) void wo_mfma(const u16* __restrict__ Ah_g,
                                               const u16* __restrict__ Al_g,
                                               const u16* __restrict__ Bh_g,
                                               const u16* __restrict__ Bl_g,
                                               const float* __restrict__ bias,
                                               float* __restrict__ C) {
  __shared__ u16 Ah[128][40], Al[128][40], Bh[128][40], Bl[128][40];
  int tid = threadIdx.x;
  int w = tid >> 6, l = tid & 63;
  int wr = w >> 1, wc = w & 1;
  int lg = l >> 4, lx = l & 15;
  int f = blockIdx.x;
  int xcd = f & 7, rr = f >> 3;        // rr 0..15
  int m0 = (xcd * 4 + (rr & 3)) * 128;
  int n0 = (rr >> 2) * 128;
  int sr = tid >> 1, s16 = (tid & 1) * 16;
  const u16* Aph = Ah_g + (size_t)(m0 + sr) * 512;
  const u16* Apl = Al_g + (size_t)(m0 + sr) * 512;
  const u16* Bph = Bh_g + (size_t)(n0 + sr) * 512;
  const u16* Bpl = Bl_g + (size_t)(n0 + sr) * 512;
  f32x4 acc[4][4];
#pragma unroll
  for (int m = 0; m < 4; ++m)
#pragma unroll
    for (int n = 0; n < 4; ++n) acc[m][n] = (f32x4){0.f, 0.f, 0.f, 0.f};
  short8 ah0 = *(const short8*)&Aph[s16];
  short8 ah1 = *(const short8*)&Aph[s16 + 8];
  short8 al0 = *(const short8*)&Apl[s16];
  short8 al1 = *(const short8*)&Apl[s16 + 8];
  short8 bh0 = *(const short8*)&Bph[s16];
  short8 bh1 = *(const short8*)&Bph[s16 + 8];
  short8 bl0 = *(const short8*)&Bpl[s16];
  short8 bl1 = *(const short8*)&Bpl[s16 + 8];
  for (int k0 = 0; k0 < 512; k0 += 32) {
    __syncthreads();
    *(short8*)&Ah[sr][s16] = ah0; *(short8*)&Ah[sr][s16 + 8] = ah1;
    *(short8*)&Al[sr][s16] = al0; *(short8*)&Al[sr][s16 + 8] = al1;
    *(short8*)&Bh[sr][s16] = bh0; *(short8*)&Bh[sr][s16 + 8] = bh1;
    *(short8*)&Bl[sr][s16] = bl0; *(short8*)&Bl[sr][s16 + 8] = bl1;
    __syncthreads();
    if (k0 + 32 < 512) {
      int ko = k0 + 32 + s16;
      ah0 = *(const short8*)&Aph[ko]; ah1 = *(const short8*)&Aph[ko + 8];
      al0 = *(const short8*)&Apl[ko]; al1 = *(const short8*)&Apl[ko + 8];
      bh0 = *(const short8*)&Bph[ko]; bh1 = *(const short8*)&Bph[ko + 8];
      bl0 = *(const short8*)&Bpl[ko]; bl1 = *(const short8*)&Bpl[ko + 8];
    }
    short8 fah[4], fal[4], fbh[4], fbl[4];
#pragma unroll
    for (int m = 0; m < 4; ++m) {
      fah[m] = *(const short8*)&Ah[wr * 64 + m * 16 + lx][lg * 8];
      fal[m] = *(const short8*)&Al[wr * 64 + m * 16 + lx][lg * 8];
    }
#pragma unroll
    for (int n = 0; n < 4; ++n) {
      fbh[n] = *(const short8*)&Bh[wc * 64 + n * 16 + lx][lg * 8];
      fbl[n] = *(const short8*)&Bl[wc * 64 + n * 16 + lx][lg * 8];
    }
#pragma unroll
    for (int m = 0; m < 4; ++m)
#pragma unroll
      for (int n = 0; n < 4; ++n) {
        acc[m][n] = __builtin_amdgcn_mfma_f32_16x16x32_bf16(fah[m], fbh[n], acc[m][n], 0, 0, 0);
        acc[m][n] = __builtin_amdgcn_mfma_f32_16x16x32_bf16(fal[m], fbh[n], acc[m][n], 0, 0, 0);
        acc[m][n] = __builtin_amdgcn_mfma_f32_16x16x32_bf16(fah[m], fbl[n], acc[m][n], 0, 0, 0);
      }
  }
#pragma unroll
  for (int m = 0; m < 4; ++m)
#pragma unroll
    for (int i = 0; i < 4; ++i) {
      int row = m0 + wr * 64 + m * 16 + lg * 4 + i;
#pragma unroll
      for (int n = 0; n < 4; ++n) {
        int col = n0 + wc * 64 + n * 16 + lx;
        C[(size_t)row * 512 + col] = acc[m][n][i] + bias[col];
      }
    }
}

// ---------------------------------------------------------------------------
// LayerNorm with residual + bf16 copy + FUSED gate top-2.
// ---------------------------------------------------------------------------
__global__ __launch_bounds__(256) void ln_res_gate(const float* __restrict__ a,
                                                   const float* __restrict__ b,
                                                   const float* __restrict__ g,
                                                   const float* __restrict__ beta,
                                                   const float* __restrict__ Wg,
                                                   float* __restrict__ out,
                                                   u16* __restrict__ obf,
                                                   float* __restrict__ gp,
                                                   int* __restrict__ tope) {
  int n = blockIdx.x * 4 + (threadIdx.x >> 6);
  int lane = threadIdx.x & 63;
  float v[8];
  float s = 0.f;
#pragma unroll
  for (int i = 0; i < 8; ++i) {
    int d = lane + 64 * i;
    v[i] = a[(size_t)n * D_ + d] + b[(size_t)n * D_ + d];
    s += v[i];
  }
#pragma unroll
  for (int m = 32; m; m >>= 1) s += __shfl_xor(s, m);
  float mean = s * (1.f / D_);
  float s2 = 0.f;
#pragma unroll
  for (int i = 0; i < 8; ++i) { float t = v[i] - mean; s2 += t * t; }
#pragma unroll
  for (int m = 32; m; m >>= 1) s2 += __shfl_xor(s2, m);
  float r = rsqrtf(s2 * (1.f / D_) + 1e-5f);
  float p[E_] = {};
#pragma unroll
  for (int i = 0; i < 8; ++i) {
    int d = lane + 64 * i;
    float val = (v[i] - mean) * r * g[d] + beta[d];
    out[(size_t)n * D_ + d] = val;
    obf[(size_t)n * D_ + d] = f2bf(val);
    const float* wr = &Wg[(size_t)d * E_];
#pragma unroll
    for (int e = 0; e < E_; ++e) p[e] += val * wr[e];
  }
#pragma unroll
  for (int e = 0; e < E_; ++e)
#pragma unroll
    for (int m = 32; m; m >>= 1) p[e] += __shfl_xor(p[e], m);
  if (lane == 0) {
    float mx = p[0];
#pragma unroll
    for (int e = 1; e < E_; ++e) mx = fmaxf(mx, p[e]);
    float q[E_];
#pragma unroll
    for (int e = 0; e < E_; ++e) q[e] = expf(p[e] - mx);
    int e1 = 0;
#pragma unroll
    for (int e = 1; e < E_; ++e) if (q[e] > q[e1]) e1 = e;
    int e2 = (e1 == 0) ? 1 : 0;
#pragma unroll
    for (int e = 0; e < E_; ++e) if (e != e1 && q[e] > q[e2]) e2 = e;
    float denom = q[e1] + q[e2];
    gp[n * 2] = q[e1] / denom;
    gp[n * 2 + 1] = q[e2] / denom;
    tope[n] = e1 | (e2 << 8);
  }
}

__global__ __launch_bounds__(256) void ln2_final(const float* __restrict__ x,
                                                 const u16* __restrict__ mp,
                                                 const float* __restrict__ g,
                                                 const float* __restrict__ beta,
                                                 float* __restrict__ out) {
  int n = blockIdx.x * 4 + (threadIdx.x >> 6);
  int lane = threadIdx.x & 63;
  float v[8];
  float s = 0.f;
#pragma unroll
  for (int i = 0; i < 8; ++i) {
    int d = lane + 64 * i;
    v[i] = x[(size_t)n * D_ + d] + bf2f(mp[(size_t)(2 * n) * D_ + d]) +
           bf2f(mp[(size_t)(2 * n + 1) * D_ + d]);
    s += v[i];
  }
#pragma unroll
  for (int m = 32; m; m >>= 1) s += __shfl_xor(s, m);
  float mean = s * (1.f / D_);
  float s2 = 0.f;
#pragma unroll
  for (int i = 0; i < 8; ++i) { float t = v[i] - mean; s2 += t * t; }
#pragma unroll
  for (int m = 32; m; m >>= 1) s2 += __shfl_xor(s2, m);
  float r = rsqrtf(s2 * (1.f / D_) + 1e-5f);
#pragma unroll
  for (int i = 0; i < 8; ++i) {
    int d = lane + 64 * i;
    out[(size_t)n * D_ + d] = (v[i] - mean) * r * g[d] + beta[d];
  }
}

// ---------------------------------------------------------------------------
// bf16 MFMA MoE GEMM, 64x128 tile, BK=32, 4 waves (each 64x32 out).
// Flat grid, expert = blockIdx & 7 -> expert pinned to one XCD.
// ---------------------------------------------------------------------------
template <int MODE>
__global__ __launch_bounds__(256) void moe_mfma(const u16* __restrict__ Abase,
                                                const u16* __restrict__ Wt,
                                                const float* __restrict__ bias,
                                                const float* __restrict__ gp,
                                                u16* __restrict__ outp,
                                                const int* __restrict__ cnt,
                                                const int* __restrict__ lst) {
  constexpr int K  = MODE ? 1024 : 512;
  constexpr int Nn = MODE ? 512 : 1024;
  constexpr int NT = Nn / 128;
  constexpr int NI = K / 32;
  int fidx = blockIdx.x;
  int e = fidx & 7;
  int r = fidx >> 3;
  int nt = r % NT;
  int mt = r / NT;
  int c = cnt[e];
  int m0 = mt * 64;
  if (m0 >= c) return;
  int off = 0;
#pragma unroll
  for (int i = 0; i < E_; ++i) if (i < e) off += cnt[i];
  int n0 = nt * 128;
  __shared__ u16 As[64][40];
  __shared__ u16 Bs[128][40];
  int tid = threadIdx.x;
  int w = tid >> 6, l = tid & 63;
  int lg = l >> 4, lx = l & 15;
  int arow = tid >> 2, aseg = (tid & 3) * 8;
  int brow = tid >> 1, bseg = (tid & 1) * 16;
  int ar = m0 + arow; if (ar >= c) ar = c - 1;
  const u16* Ap;
  if (MODE == 0) Ap = Abase + (size_t)(lst[e * N_ + ar] >> 1) * 512 + aseg;
  else           Ap = Abase + (size_t)(off + ar) * 1024 + aseg;
  const u16* Bp = Wt + (size_t)e * K * Nn + (size_t)(n0 + brow) * K + bseg;

  f32x4 acc[4][2];
#pragma unroll
  for (int m = 0; m < 4; ++m)
#pragma unroll
    for (int n = 0; n < 2; ++n) acc[m][n] = (f32x4){0.f, 0.f, 0.f, 0.f};

  short8 pa  = *(const short8*)&Ap[0];
  short8 pb0 = *(const short8*)&Bp[0];
  short8 pb1 = *(const short8*)&Bp[8];
  for (int kk = 0; kk < NI; ++kk) {
    __syncthreads();
    *(short8*)&As[arow][aseg] = pa;
    *(short8*)&Bs[brow][bseg] = pb0;
    *(short8*)&Bs[brow][bseg + 8] = pb1;
    __syncthreads();
    if (kk + 1 < NI) {
      int ko = (kk + 1) * 32;
      pa  = *(const short8*)&Ap[ko];
      pb0 = *(const short8*)&Bp[ko];
      pb1 = *(const short8*)&Bp[ko + 8];
    }
    short8 af[4], bf[2];
#pragma unroll
    for (int m = 0; m < 4; ++m)
      af[m] = *(const short8*)&As[m * 16 + lx][lg * 8];
#pragma unroll
    for (int n = 0; n < 2; ++n)
      bf[n] = *(const short8*)&Bs[w * 32 + n * 16 + lx][lg * 8];
#pragma unroll
    for (int m = 0; m < 4; ++m)
#pragma unroll
      for (int n = 0; n < 2; ++n)
        acc[m][n] = __builtin_amdgcn_mfma_f32_16x16x32_bf16(af[m], bf[n], acc[m][n], 0, 0, 0);
  }
#pragma unroll
  for (int m = 0; m < 4; ++m)
#pragma unroll
    for (int i = 0; i < 4; ++i) {
      int rr = m0 + m * 16 + lg * 4 + i;
      if (rr < c) {
#pragma unroll
        for (int n = 0; n < 2; ++n) {
          int col = n0 + w * 32 + n * 16 + lx;
          float val = acc[m][n][i] + bias[e * Nn + col];
          if (MODE == 0) {
            outp[(size_t)(off + rr) * 1024 + col] = f2bf(fmaxf(val, 0.f));
          } else {
            int p = lst[e * N_ + rr];
            outp[(size_t)p * 512 + col] = f2bf(gp[p] * val);
          }
        }
      }
    }
}

// ---------------------------------------------------------------------------
extern "C" void kernel_launch(void* const* d_in, const int* in_sizes, int n_in,
                              void* d_out, int out_size, void* d_ws, size_t ws_size,
                              hipStream_t stream) {
  const float* src  = (const float*)d_in[0];
  const float* cosb = (const float*)d_in[1];
  const float* sinb = (const float*)d_in[2];
  const float* Wq   = (const float*)d_in[3];
  const float* bq   = (const float*)d_in[4];
  const float* Wk   = (const float*)d_in[5];
  const float* bk   = (const float*)d_in[6];
  const float* Wv   = (const float*)d_in[7];
  const float* bv   = (const float*)d_in[8];
  const float* Wo   = (const float*)d_in[9];
  const float* bo   = (const float*)d_in[10];
  const float* ln1g = (const float*)d_in[11];
  const float* ln1b = (const float*)d_in[12];
  const float* ln2g = (const float*)d_in[13];
  const float* ln2b = (const float*)d_in[14];
  const float* Wg   = (const float*)d_in[15];
  const float* W1   = (const float*)d_in[16];
  const float* B1   = (const float*)d_in[17];
  const float* W2   = (const float*)d_in[18];
  const float* B2   = (const float*)d_in[19];
  float* out = (float*)d_out;
  char* wsb = (char*)d_ws;

  const size_t MB1 = 1u << 20;
  u16* sh   = (u16*)(wsb + 0 * MB1);      // src hi  [0,4M)   ; later ch, then mp
  u16* sl   = (u16*)(wsb + 4 * MB1);      // src lo  [4,8M)   ; later cl
  u16* qhb  = (u16*)(wsb + 8 * MB1);      // [8,12M)          ; later hbf part
  u16* qlb  = (u16*)(wsb + 12 * MB1);
  u16* khb  = (u16*)(wsb + 16 * MB1);
  u16* klb  = (u16*)(wsb + 20 * MB1);
  u16* vbuf = (u16*)(wsb + 24 * MB1);     // [24,28M)
  u16* poh  = (u16*)(wsb + 28 * MB1);     // [28,36M) attn partial hi ; later aob f32, then W2t
  u16* pol  = (u16*)(wsb + 36 * MB1);     // [36,44M) attn partial lo ; later xb f32
  float* pml = (float*)(wsb + 44 * MB1);  // [44,44.5M)       ; later xbf
  float* aob = (float*)(wsb + 28 * MB1);  // [28,36M)
  float* xb  = (float*)(wsb + 36 * MB1);  // [36,44M)
  u16* xbf   = (u16*)(wsb + 44 * MB1);    // [44,48M)
  u16* Wqkv_hi = (u16*)(wsb + 48 * MB1);              // 1.5MB
  u16* Wqkv_lo = (u16*)(wsb + 48 * MB1 + 1572864);    // 1.5MB
  u16* Wo_hi   = (u16*)(wsb + 48 * MB1 + 3145728);    // 0.5MB
  u16* Wo_lo   = (u16*)(wsb + 48 * MB1 + 3670016);    // 0.5MB
  u16* W1t     = (u16*)(wsb + 52 * MB1);  // [52,60M)
  u16* W2t     = (u16*)(wsb + 28 * MB1);  // [28,36M) — written after ln_res_gate (aob dead)
  float* gpb   = (float*)(wsb + 60 * MB1);                 // 32 KB
  int* cnt     = (int*)(wsb + 60 * MB1 + 32768);           // 64 B
  int* lst     = (int*)(wsb + 60 * MB1 + 32768 + 64);      // 128 KB
  int* tope    = (int*)(wsb + 60 * MB1 + 32768 + 64 + 131072);  // 16 KB
  u16* ch  = sh;                          // ctx hi aliases src-split (dead)
  u16* cl  = sl;
  u16* hbf = (u16*)(wsb + 8 * MB1);       // [8,24M) aliases q/k (dead after attn)
  u16* mp  = (u16*)(wsb + 0 * MB1);       // [0,8M)  aliases ch/cl (dead after wo)

  dim3 blk(256);
  // Weight splits + src split in ONE launch
  wsplit_all<<<dim3(8, 8, 20), blk, 0, stream>>>(Wq, Wk, Wv, Wo, src,
                                                 Wqkv_hi, Wqkv_lo, Wo_hi, Wo_lo,
                                                 sh, sl);
  // QKV + RoPE fused (split-bf16; V-blocks 2-product), XCD-pinned flat grid
  qkv_mfma<<<dim3(384), blk, 0, stream>>>(sh, sl, Wqkv_hi, Wqkv_lo, bq, bk, bv,
                                          cosb, sinb, qhb, qlb, khb, klb, vbuf);
  // Attention, KV-split=2, XCD-pinned slabs, QT=128, KT=128
  attn_mfma2<<<dim3(512), dim3(512), 0, stream>>>(qhb, qlb, khb, klb, vbuf, poh, pol, pml);
  merge_attn2<<<dim3(2048), blk, 0, stream>>>(poh, pol, pml, ch, cl);
  // Wo projection (split-bf16), XCD-pinned flat grid
  wo_mfma<<<dim3(128), blk, 0, stream>>>(ch, cl, Wo_hi, Wo_lo, bo, aob);
  // LN1 + fused gate top-2
  ln_res_gate<<<dim3(1024), blk, 0, stream>>>(src, aob, ln1g, ln1b, Wg, xb, xbf, gpb, tope);
  // MoE weight transposes + ordered routing in ONE launch
  wtrans_all<<<dim3(16, 16, 17), blk, 0, stream>>>(W1, W2, W1t, W2t, tope, cnt, lst);
  // Sparse MoE expert GEMMs — 64x128 tiles, expert pinned to XCD
  moe_mfma<0><<<dim3(8 * 8 * 64), blk, 0, stream>>>(xbf, W1t, B1, gpb, hbf, cnt, lst);
  moe_mfma<1><<<dim3(8 * 4 * 64), blk, 0, stream>>>(hbf, W2t, B2, gpb, mp, cnt, lst);
  ln2_final<<<dim3(1024), blk, 0, stream>>>(xb, mp, ln2g, ln2b, out);
}